// Round 2
// baseline (430.266 us; speedup 1.0000x reference)
//
#include <hip/hip_runtime.h>

#define HID 128
#define NPTS 32768
#define NIC  16384
#define GRID 256
#define BLK  512
#define NW   8  // waves per block

__device__ __forceinline__ float tanh_fast(float x) {
    // 1 - 2/(e^{2x}+1); exact limits at +-inf, no branches
    float e = __expf(2.0f * x);
    return 1.0f - 2.0f / (e + 1.0f);
}

__device__ __forceinline__ float wave_allsum(float v) {
#pragma unroll
    for (int off = 32; off > 0; off >>= 1) v += __shfl_xor(v, off, 64);
    return v;
}

// stage a 128x128 fp32 weight matrix (64KB) global -> LDS, 512 threads
__device__ __forceinline__ void stage_w(float* dst, const float* __restrict__ src, int tid) {
    const float4* s4 = (const float4*)src;
    float4* d4 = (float4*)dst;
#pragma unroll
    for (int k = 0; k < 8; k++) d4[tid + k * BLK] = s4[tid + k * BLK];
}

// layer 0 for one point: (x,y,t) -> 128 neurons. sSm: W0[3*128] at 0, B0 at 384.
// channels: 0=val 1=dx 2=dy 3=dt 4=dxx 5=dyy
template <int NCH>
__device__ __forceinline__ void layer0_pt(const float* sSm, float x, float y, float t,
                                          float* hp, int lane) {
    const int n0 = lane * 2;
#pragma unroll
    for (int tt = 0; tt < 2; tt++) {
        const int n = n0 + tt;
        const float wx = sSm[n], wy = sSm[HID + n], wz = sSm[2 * HID + n];
        const float z = sSm[3 * HID + n] + wx * x + wy * y + wz * t;
        const float a = tanh_fast(z);
        if (NCH == 6) {
            const float s = 1.f - a * a;
            hp[0 * HID + n] = a;
            hp[1 * HID + n] = s * wx;
            hp[2 * HID + n] = s * wy;
            hp[3 * HID + n] = s * wz;
            hp[4 * HID + n] = -2.f * a * s * wx * wx;  // z_xx = 0
            hp[5 * HID + n] = -2.f * a * s * wy * wy;  // z_yy = 0
        } else {
            hp[n] = a;
        }
    }
}

// one 128x128 hidden layer, 6 dual channels, ONE point, per-wave (no barriers).
// In-place on hp: all LDS reads (program order, whole wave) precede the writes.
__device__ __forceinline__ void hidden6(const float* sW, float* hp, const float* sB, int lane) {
    const int n0 = lane * 2;
    float a0[6], a1[6];
#pragma unroll
    for (int c = 0; c < 6; c++) { a0[c] = 0.f; a1[c] = 0.f; }
#pragma unroll 8
    for (int j = 0; j < HID; j += 4) {
        const float2 wa = *(const float2*)&sW[(j + 0) * HID + n0];
        const float2 wb = *(const float2*)&sW[(j + 1) * HID + n0];
        const float2 wc = *(const float2*)&sW[(j + 2) * HID + n0];
        const float2 wd = *(const float2*)&sW[(j + 3) * HID + n0];
#pragma unroll
        for (int c = 0; c < 6; c++) {
            const float4 h = *(const float4*)&hp[c * HID + j];
            a0[c] = fmaf(wa.x, h.x, fmaf(wb.x, h.y, fmaf(wc.x, h.z, fmaf(wd.x, h.w, a0[c]))));
            a1[c] = fmaf(wa.y, h.x, fmaf(wb.y, h.y, fmaf(wc.y, h.z, fmaf(wd.y, h.w, a1[c]))));
        }
    }
    const float b0v = sB[n0], b1v = sB[n0 + 1];
    const float z0 = a0[0] + b0v, z1 = a1[0] + b1v;
    const float t0 = tanh_fast(z0), t1 = tanh_fast(z1);
    const float s0 = 1.f - t0 * t0, s1 = 1.f - t1 * t1;
    *(float2*)&hp[0 * HID + n0] = make_float2(t0, t1);
    *(float2*)&hp[1 * HID + n0] = make_float2(s0 * a0[1], s1 * a1[1]);
    *(float2*)&hp[2 * HID + n0] = make_float2(s0 * a0[2], s1 * a1[2]);
    *(float2*)&hp[3 * HID + n0] = make_float2(s0 * a0[3], s1 * a1[3]);
    *(float2*)&hp[4 * HID + n0] = make_float2(
        s0 * a0[4] - 2.f * t0 * s0 * a0[1] * a0[1],
        s1 * a1[4] - 2.f * t1 * s1 * a1[1] * a1[1]);
    *(float2*)&hp[5 * HID + n0] = make_float2(
        s0 * a0[5] - 2.f * t0 * s0 * a0[2] * a0[2],
        s1 * a1[5] - 2.f * t1 * s1 * a1[2] * a1[2]);
}

// value-only hidden layer, 4 points (contiguous hp[p*HID]), per-wave, in-place.
__device__ __forceinline__ void hidden1_p4(const float* sW, float* hp, const float* sB, int lane) {
    const int n0 = lane * 2;
    float a0[4], a1[4];
#pragma unroll
    for (int p = 0; p < 4; p++) { a0[p] = 0.f; a1[p] = 0.f; }
#pragma unroll 8
    for (int j = 0; j < HID; j += 4) {
        const float2 wa = *(const float2*)&sW[(j + 0) * HID + n0];
        const float2 wb = *(const float2*)&sW[(j + 1) * HID + n0];
        const float2 wc = *(const float2*)&sW[(j + 2) * HID + n0];
        const float2 wd = *(const float2*)&sW[(j + 3) * HID + n0];
#pragma unroll
        for (int p = 0; p < 4; p++) {
            const float4 h = *(const float4*)&hp[p * HID + j];
            a0[p] = fmaf(wa.x, h.x, fmaf(wb.x, h.y, fmaf(wc.x, h.z, fmaf(wd.x, h.w, a0[p]))));
            a1[p] = fmaf(wa.y, h.x, fmaf(wb.y, h.y, fmaf(wc.y, h.z, fmaf(wd.y, h.w, a1[p]))));
        }
    }
    const float b0v = sB[n0], b1v = sB[n0 + 1];
#pragma unroll
    for (int p = 0; p < 4; p++) {
        *(float2*)&hp[p * HID + n0] =
            make_float2(tanh_fast(a0[p] + b0v), tanh_fast(a1[p] + b1v));
    }
}

// ---------------- n-net: mu = 0.01*n(x)^2, plus sum(mu^2) partials ----------------
__global__ __launch_bounds__(BLK) void k_mu(
    const float* __restrict__ xtr,
    const float* __restrict__ nw0, const float* __restrict__ nb0,
    const float* __restrict__ nw1, const float* __restrict__ nb1,
    const float* __restrict__ nw2, const float* __restrict__ nb2,
    const float* __restrict__ nw3, const float* __restrict__ nb3,
    float* __restrict__ muArr, float* __restrict__ muPart) {
    __shared__ __align__(16) float sW1[HID * HID];
    __shared__ __align__(16) float sW2[HID * HID];
    __shared__ __align__(16) float sH[NW * 4 * HID];
    __shared__ __align__(16) float sSm[897];
    __shared__ float sRed[NW];

    const int tid = threadIdx.x;
    const int lane = tid & 63;
    const int wv = tid >> 6;

    stage_w(sW1, nw1, tid);
    stage_w(sW2, nw2, tid);
    for (int i = tid; i < 384; i += BLK) sSm[i] = nw0[i];
    for (int i = tid; i < HID; i += BLK) {
        sSm[384 + i] = nb0[i];
        sSm[512 + i] = nb1[i];
        sSm[640 + i] = nb2[i];
        sSm[768 + i] = nw3[i];
    }
    if (tid == 0) sSm[896] = nb3[0];
    __syncthreads();  // the only barrier before the final reduce

    float accMu2 = 0.f;
    const int wgpt = (blockIdx.x * NW + wv) * 16;
    float* hp = &sH[wv * 4 * HID];

    for (int it = 0; it < 4; it++) {
        const int pt0 = wgpt + it * 4;
#pragma unroll
        for (int p = 0; p < 4; p++) {
            const float x = xtr[(pt0 + p) * 3 + 0];
            const float y = xtr[(pt0 + p) * 3 + 1];
            const float t = xtr[(pt0 + p) * 3 + 2];
            layer0_pt<1>(sSm, x, y, t, hp + p * HID, lane);
        }
        hidden1_p4(sW1, hp, &sSm[512], lane);
        hidden1_p4(sW2, hp, &sSm[640], lane);
#pragma unroll
        for (int p = 0; p < 4; p++) {
            float o = 0.f;
#pragma unroll
            for (int jj = 0; jj < 2; jj++) {
                const int j = lane + jj * 64;
                o = fmaf(sSm[768 + j], hp[p * HID + j], o);
            }
            o = wave_allsum(o);
            o += sSm[896];
            const float muv = 0.01f * o * o;
            if (lane == 0) muArr[pt0 + p] = muv;
            accMu2 += muv * muv;  // identical on all lanes
        }
    }
    if (lane == 0) sRed[wv] = accMu2;
    __syncthreads();
    if (tid == 0) {
        float s = 0.f;
#pragma unroll
        for (int w = 0; w < NW; w++) s += sRed[w];
        muPart[blockIdx.x] = s;
    }
}

// ---------------- m-net with 6 dual channels -> PDE residual partials ----------------
__global__ __launch_bounds__(BLK) void k_residual(
    const float* __restrict__ xtr,
    const float* __restrict__ mw0, const float* __restrict__ mb0,
    const float* __restrict__ mw1, const float* __restrict__ mb1,
    const float* __restrict__ mw2, const float* __restrict__ mb2,
    const float* __restrict__ mw3, const float* __restrict__ mb3,
    const float* __restrict__ muArr, float* __restrict__ resPart) {
    __shared__ __align__(16) float sW1[HID * HID];
    __shared__ __align__(16) float sW2[HID * HID];
    __shared__ __align__(16) float sH[NW * 6 * HID];
    __shared__ __align__(16) float sSm[1284];
    __shared__ float sRed[NW][4];

    const int tid = threadIdx.x;
    const int lane = tid & 63;
    const int wv = tid >> 6;

    // sSm: W0:0(384) B0:384 B1:512 B2:640 W3:768(512) B3:1280(4)
    stage_w(sW1, mw1, tid);
    stage_w(sW2, mw2, tid);
    for (int i = tid; i < 384; i += BLK) sSm[i] = mw0[i];
    for (int i = tid; i < HID; i += BLK) {
        sSm[384 + i] = mb0[i];
        sSm[512 + i] = mb1[i];
        sSm[640 + i] = mb2[i];
    }
    for (int i = tid; i < 512; i += BLK) sSm[768 + i] = mw3[i];
    if (tid < 4) sSm[1280 + tid] = mb3[tid];
    __syncthreads();  // the only barrier before the final reduce

    float racc[4] = {0.f, 0.f, 0.f, 0.f};
    const int wgpt = (blockIdx.x * NW + wv) * 16;
    float* hp = &sH[wv * 6 * HID];

    for (int i = 0; i < 16; i++) {
        const int pt = wgpt + i;
        {
            const float x = xtr[pt * 3 + 0];
            const float y = xtr[pt * 3 + 1];
            const float t = xtr[pt * 3 + 2];
            layer0_pt<6>(sSm, x, y, t, hp, lane);
        }
        hidden6(sW1, hp, &sSm[512], lane);
        hidden6(sW2, hp, &sSm[640], lane);

        // final linear layer (128->4, all 6 channels) + residual math
        float oq[4][6];
#pragma unroll
        for (int k = 0; k < 4; k++)
#pragma unroll
            for (int c = 0; c < 6; c++) oq[k][c] = 0.f;
#pragma unroll
        for (int jj = 0; jj < 2; jj++) {
            const int j = lane + jj * 64;
            const float4 w3 = *(const float4*)&sSm[768 + j * 4];
#pragma unroll
            for (int c = 0; c < 6; c++) {
                const float h = hp[c * HID + j];
                oq[0][c] = fmaf(w3.x, h, oq[0][c]);
                oq[1][c] = fmaf(w3.y, h, oq[1][c]);
                oq[2][c] = fmaf(w3.z, h, oq[2][c]);
                oq[3][c] = fmaf(w3.w, h, oq[3][c]);
            }
        }
#pragma unroll
        for (int k = 0; k < 4; k++)
#pragma unroll
            for (int c = 0; c < 6; c++) oq[k][c] = wave_allsum(oq[k][c]);
#pragma unroll
        for (int k = 0; k < 4; k++) oq[k][0] += sSm[1280 + k];

        const float rho = oq[0][0], rho_x = oq[0][1], rho_y = oq[0][2],
                    rho_t = oq[0][3], rho_xx = oq[0][4], rho_yy = oq[0][5];
        const float pr = oq[1][0], pr_x = oq[1][1], pr_y = oq[1][2],
                    pr_t = oq[1][3], pr_xx = oq[1][4], pr_yy = oq[1][5];
        const float u = oq[2][0], u_x = oq[2][1], u_y = oq[2][2],
                    u_t = oq[2][3], u_xx = oq[2][4], u_yy = oq[2][5];
        const float v = oq[3][0], v_x = oq[3][1], v_y = oq[3][2],
                    v_t = oq[3][3], v_xx = oq[3][4], v_yy = oq[3][5];

        const float ig1 = 2.5f;  // 1/(gamma-1)
        const float ke = 0.5f * (u * u + v * v);
        const float E = pr * ig1 + rho * ke;
        const float d_x = u * u_x + v * v_x;
        const float d_y = u * u_y + v * v_y;
        const float d_t = u * u_t + v * v_t;
        const float E_x = pr_x * ig1 + rho_x * ke + rho * d_x;
        const float E_y = pr_y * ig1 + rho_y * ke + rho * d_y;
        const float E_t = pr_t * ig1 + rho_t * ke + rho * d_t;
        const float E_xx = pr_xx * ig1 + rho_xx * ke + 2.f * rho_x * d_x +
                           rho * (u_x * u_x + u * u_xx + v_x * v_x + v * v_xx);
        const float E_yy = pr_yy * ig1 + rho_yy * ke + 2.f * rho_y * d_y +
                           rho * (u_y * u_y + u * u_yy + v_y * v_y + v * v_yy);

        const float m = muArr[pt];

        const float r1 = rho_t + (rho_x * u + rho * u_x) + (rho_y * v + rho * v_y)
                       - m * (rho_xx + rho_yy);
        const float r2 = (rho_t * u + rho * u_t)
                       + (rho_x * u * u + 2.f * rho * u * u_x + pr_x)
                       + (rho_y * u * v + rho * u_y * v + rho * u * v_y)
                       - m * ((rho_xx * u + 2.f * rho_x * u_x + rho * u_xx)
                            + (rho_yy * u + 2.f * rho_y * u_y + rho * u_yy));
        const float r3 = (rho_t * v + rho * v_t)
                       + (rho_x * u * v + rho * u_x * v + rho * u * v_x)
                       + (rho_y * v * v + 2.f * rho * v * v_y + pr_y)
                       - m * ((rho_xx * v + 2.f * rho_x * v_x + rho * v_xx)
                            + (rho_yy * v + 2.f * rho_y * v_y + rho * v_yy));
        const float r4 = E_t
                       + (u_x * (E + pr) + u * (E_x + pr_x))
                       + (v_y * (E + pr) + v * (E_y + pr_y))
                       - m * (E_xx + E_yy);

        racc[0] += r1 * r1;
        racc[1] += r2 * r2;
        racc[2] += r3 * r3;
        racc[3] += r4 * r4;
    }

    if (lane == 0) {
        sRed[wv][0] = racc[0]; sRed[wv][1] = racc[1];
        sRed[wv][2] = racc[2]; sRed[wv][3] = racc[3];
    }
    __syncthreads();
    if (tid == 0) {
        float s0 = 0, s1 = 0, s2 = 0, s3 = 0;
#pragma unroll
        for (int w = 0; w < NW; w++) {
            s0 += sRed[w][0]; s1 += sRed[w][1]; s2 += sRed[w][2]; s3 += sRed[w][3];
        }
        resPart[blockIdx.x * 4 + 0] = s0;
        resPart[blockIdx.x * 4 + 1] = s1;
        resPart[blockIdx.x * 4 + 2] = s2;
        resPart[blockIdx.x * 4 + 3] = s3;
    }
}

// ---------------- IC branch: m-net value-only on x_initial, quadrant sums ----------------
__global__ __launch_bounds__(BLK) void k_ic(
    const float* __restrict__ xin,
    const float* __restrict__ mw0, const float* __restrict__ mb0,
    const float* __restrict__ mw1, const float* __restrict__ mb1,
    const float* __restrict__ mw2, const float* __restrict__ mb2,
    const float* __restrict__ mw3, const float* __restrict__ mb3,
    const float* __restrict__ icg, float* __restrict__ icPart) {
    __shared__ __align__(16) float sW1[HID * HID];
    __shared__ __align__(16) float sW2[HID * HID];
    __shared__ __align__(16) float sH[NW * 4 * HID];
    __shared__ __align__(16) float sSm[1284];
    __shared__ float sTq[16];
    __shared__ float sRed[NW][8];

    const int tid = threadIdx.x;
    const int lane = tid & 63;
    const int wv = tid >> 6;

    stage_w(sW1, mw1, tid);
    stage_w(sW2, mw2, tid);
    for (int i = tid; i < 384; i += BLK) sSm[i] = mw0[i];
    for (int i = tid; i < HID; i += BLK) {
        sSm[384 + i] = mb0[i];
        sSm[512 + i] = mb1[i];
        sSm[640 + i] = mb2[i];
    }
    for (int i = tid; i < 512; i += BLK) sSm[768 + i] = mw3[i];
    if (tid < 4) sSm[1280 + tid] = mb3[tid];
    if (tid < 16) {
        // quad 0: xl&yt -> ic row 1; quad 1: xr&yt -> row 3;
        // quad 2: xl&yb -> row 0; quad 3: xr&yb -> row 2; perm = [0,3,1,2]
        const int k = tid & 3, q = tid >> 2;
        const int row = (q == 0) ? 1 : ((q == 1) ? 3 : ((q == 2) ? 0 : 2));
        const int pc = (k == 0) ? 0 : ((k == 1) ? 3 : ((k == 2) ? 1 : 2));
        sTq[q * 4 + k] = icg[row * 4 + pc];
    }
    __syncthreads();

    float qs[4] = {0, 0, 0, 0}, qc[4] = {0, 0, 0, 0};
    const int wgpt = (blockIdx.x * NW + wv) * 8;
    float* hp = &sH[wv * 4 * HID];

    for (int it = 0; it < 2; it++) {
        const int pt0 = wgpt + it * 4;
#pragma unroll
        for (int p = 0; p < 4; p++) {
            const float x = xin[(pt0 + p) * 3 + 0];
            const float y = xin[(pt0 + p) * 3 + 1];
            const float t = xin[(pt0 + p) * 3 + 2];
            layer0_pt<1>(sSm, x, y, t, hp + p * HID, lane);
        }
        hidden1_p4(sW1, hp, &sSm[512], lane);
        hidden1_p4(sW2, hp, &sSm[640], lane);

#pragma unroll
        for (int p = 0; p < 4; p++) {
            float o0 = 0, o1 = 0, o2 = 0, o3 = 0;
#pragma unroll
            for (int jj = 0; jj < 2; jj++) {
                const int j = lane + jj * 64;
                const float4 w3 = *(const float4*)&sSm[768 + j * 4];
                const float h = hp[p * HID + j];
                o0 = fmaf(w3.x, h, o0);
                o1 = fmaf(w3.y, h, o1);
                o2 = fmaf(w3.z, h, o2);
                o3 = fmaf(w3.w, h, o3);
            }
            o0 = wave_allsum(o0); o1 = wave_allsum(o1);
            o2 = wave_allsum(o2); o3 = wave_allsum(o3);
            o0 += sSm[1280]; o1 += sSm[1281]; o2 += sSm[1282]; o3 += sSm[1283];

            const float x = xin[(pt0 + p) * 3 + 0];
            const float y = xin[(pt0 + p) * 3 + 1];
            int quad = -1;
            if (x < 0.5f && y > 0.5f) quad = 0;
            else if (x > 0.5f && y > 0.5f) quad = 1;
            else if (x < 0.5f && y < 0.5f) quad = 2;
            else if (x > 0.5f && y < 0.5f) quad = 3;
            if (quad >= 0) {  // wave-uniform branch
                const float d0 = o0 - sTq[quad * 4 + 0];
                const float d1 = o1 - sTq[quad * 4 + 1];
                const float d2 = o2 - sTq[quad * 4 + 2];
                const float d3 = o3 - sTq[quad * 4 + 3];
                const float ss = d0 * d0 + d1 * d1 + d2 * d2 + d3 * d3;
#pragma unroll
                for (int q = 0; q < 4; q++) {
                    qs[q] += (quad == q) ? ss : 0.f;
                    qc[q] += (quad == q) ? 1.f : 0.f;
                }
            }
        }
    }

    if (lane == 0) {
#pragma unroll
        for (int q = 0; q < 4; q++) { sRed[wv][q] = qs[q]; sRed[wv][4 + q] = qc[q]; }
    }
    __syncthreads();
    if (tid == 0) {
        float s[8] = {0, 0, 0, 0, 0, 0, 0, 0};
#pragma unroll
        for (int w = 0; w < NW; w++)
#pragma unroll
            for (int q = 0; q < 8; q++) s[q] += sRed[w][q];
#pragma unroll
        for (int q = 0; q < 8; q++) icPart[blockIdx.x * 8 + q] = s[q];
    }
}

// ---------------- finalize: deterministic fixed-order combine ----------------
__global__ void k_fin(const float* __restrict__ resPart, const float* __restrict__ muPart,
                      const float* __restrict__ icPart, float* __restrict__ out) {
    const int lane = threadIdx.x;  // 64 threads
    float r[4] = {0, 0, 0, 0};
    float m2 = 0.f;
    float qs[4] = {0, 0, 0, 0}, qc[4] = {0, 0, 0, 0};
    for (int b = lane; b < GRID; b += 64) {
#pragma unroll
        for (int i = 0; i < 4; i++) r[i] += resPart[b * 4 + i];
        m2 += muPart[b];
#pragma unroll
        for (int q = 0; q < 4; q++) {
            qs[q] += icPart[b * 8 + q];
            qc[q] += icPart[b * 8 + 4 + q];
        }
    }
#pragma unroll
    for (int i = 0; i < 4; i++) r[i] = wave_allsum(r[i]);
    m2 = wave_allsum(m2);
#pragma unroll
    for (int q = 0; q < 4; q++) { qs[q] = wave_allsum(qs[q]); qc[q] = wave_allsum(qc[q]); }
    if (lane == 0) {
        const float sumr = (r[0] + r[1] + r[2] + r[3]) / (float)NPTS;
        float init_loss = 0.f;
#pragma unroll
        for (int q = 0; q < 4; q++) init_loss += qs[q] / fmaxf(qc[q], 1.f);
        out[0] = sumr + 10.f * init_loss + 0.1f * (m2 / (float)NPTS);
    }
}

extern "C" void kernel_launch(void* const* d_in, const int* in_sizes, int n_in,
                              void* d_out, int out_size, void* d_ws, size_t ws_size,
                              hipStream_t stream) {
    const float* xtr = (const float*)d_in[0];
    const float* xin = (const float*)d_in[1];
    const float* icg = (const float*)d_in[2];
    const float* mw0 = (const float*)d_in[3];
    const float* mb0 = (const float*)d_in[4];
    const float* mw1 = (const float*)d_in[5];
    const float* mb1 = (const float*)d_in[6];
    const float* mw2 = (const float*)d_in[7];
    const float* mb2 = (const float*)d_in[8];
    const float* mw3 = (const float*)d_in[9];
    const float* mb3 = (const float*)d_in[10];
    const float* nw0 = (const float*)d_in[11];
    const float* nb0 = (const float*)d_in[12];
    const float* nw1 = (const float*)d_in[13];
    const float* nb1 = (const float*)d_in[14];
    const float* nw2 = (const float*)d_in[15];
    const float* nb2 = (const float*)d_in[16];
    const float* nw3 = (const float*)d_in[17];
    const float* nb3 = (const float*)d_in[18];

    float* wsf = (float*)d_ws;
    float* muArr = wsf;               // 32768
    float* resPart = wsf + 32768;     // 256*4
    float* muPart = wsf + 33792;      // 256
    float* icPart = wsf + 34048;      // 256*8

    k_mu<<<GRID, BLK, 0, stream>>>(xtr, nw0, nb0, nw1, nb1, nw2, nb2, nw3, nb3,
                                   muArr, muPart);
    k_ic<<<GRID, BLK, 0, stream>>>(xin, mw0, mb0, mw1, mb1, mw2, mb2, mw3, mb3,
                                   icg, icPart);
    k_residual<<<GRID, BLK, 0, stream>>>(xtr, mw0, mb0, mw1, mb1, mw2, mb2, mw3, mb3,
                                         muArr, resPart);
    k_fin<<<1, 64, 0, stream>>>(resPart, muPart, icPart, (float*)d_out);
}

// Round 3
// 226.931 us; speedup vs baseline: 1.8960x; 1.8960x over previous
//
#include <hip/hip_runtime.h>

#define HID 128
#define NPTS 32768
#define NIC  16384
#define GRID 256
#define BLK  512
#define NW   8

typedef unsigned int uint_t;
typedef __attribute__((ext_vector_type(8))) short bf16x8;
typedef __attribute__((ext_vector_type(4))) float f32x4;

__device__ __forceinline__ float tanh_fast(float x) {
    float e = __expf(2.0f * x);
    return 1.0f - 2.0f / (e + 1.0f);
}

__device__ __forceinline__ float wave_allsum(float v) {
#pragma unroll
    for (int off = 32; off > 0; off >>= 1) v += __shfl_xor(v, off, 64);
    return v;
}

// pack f32 -> (bf16_hi << 16) | bf16_lo  with w ~= hi + lo  (RNE both)
__device__ __forceinline__ uint_t pack_hl(float w) {
    uint_t u = __float_as_uint(w);
    uint_t hb = (u + 0x7FFFu + ((u >> 16) & 1u)) >> 16;
    float hf = __uint_as_float(hb << 16);
    float lo = w - hf;
    uint_t ul = __float_as_uint(lo);
    uint_t lb = (ul + 0x7FFFu + ((ul >> 16) & 1u)) >> 16;
    return (hb << 16) | (lb & 0xFFFFu);
}

union U8 { uint_t u[4]; bf16x8 v; };

__device__ __forceinline__ bf16x8 hi_of(const uint4 w0, const uint4 w1) {
    U8 r;
    r.u[0] = (w0.x >> 16) | (w0.y & 0xFFFF0000u);
    r.u[1] = (w0.z >> 16) | (w0.w & 0xFFFF0000u);
    r.u[2] = (w1.x >> 16) | (w1.y & 0xFFFF0000u);
    r.u[3] = (w1.z >> 16) | (w1.w & 0xFFFF0000u);
    return r.v;
}
__device__ __forceinline__ bf16x8 lo_of(const uint4 w0, const uint4 w1) {
    U8 r;
    r.u[0] = (w0.x & 0xFFFFu) | (w0.y << 16);
    r.u[1] = (w0.z & 0xFFFFu) | (w0.w << 16);
    r.u[2] = (w1.x & 0xFFFFu) | (w1.y << 16);
    r.u[3] = (w1.z & 0xFFFFu) | (w1.w << 16);
    return r.v;
}

// ---------------- prep: transpose + bf16-split + pack weights into ws ----------------
// wt: [128 n][132 j] packed words from src [128 j][128 n] f32. w3t: [16 k][132 j].
__global__ __launch_bounds__(BLK) void k_prep(
    const float* __restrict__ mw1, const float* __restrict__ mw2,
    const float* __restrict__ mw3,
    uint_t* __restrict__ wt1, uint_t* __restrict__ wt2, uint_t* __restrict__ w3t) {
    const int tid = threadIdx.x;
    if (blockIdx.x == 0) {
#pragma unroll
        for (int k = 0; k < 32; k++) {
            int idx = tid + k * BLK;
            int j = idx >> 7, n = idx & 127;
            wt1[n * 132 + j] = pack_hl(mw1[idx]);
        }
        for (int i = tid; i < 16 * 132; i += BLK) w3t[i] = 0u;
        __syncthreads();
        {
            int kk = tid >> 7, j = tid & 127;  // 512 elements exactly
            w3t[kk * 132 + j] = pack_hl(mw3[j * 4 + kk]);
        }
    } else {
#pragma unroll
        for (int k = 0; k < 32; k++) {
            int idx = tid + k * BLK;
            int j = idx >> 7, n = idx & 127;
            wt2[n * 132 + j] = pack_hl(mw2[idx]);
        }
    }
}

// ---------------- MFMA core: Z[rt*16+.. ][pt] over 6 channel tiles ----------------
__device__ __forceinline__ void mfma_layer(f32x4* acc, const uint_t* sW,
                                           const uint_t* sH, int rt, int g, int l15) {
#pragma unroll
    for (int ks = 0; ks < 4; ks++) {
        const uint_t* pa = &sW[(rt * 16 + l15) * 132 + ks * 32 + g * 8];
        const uint4 a0 = *(const uint4*)pa;
        const uint4 a1 = *(const uint4*)(pa + 4);
        const bf16x8 Ah = hi_of(a0, a1);
        const bf16x8 Al = lo_of(a0, a1);
#pragma unroll
        for (int c = 0; c < 6; c++) {
            const uint_t* pb = &sH[c * 2112 + l15 * 132 + ks * 32 + g * 8];
            const uint4 b0 = *(const uint4*)pb;
            const uint4 b1 = *(const uint4*)(pb + 4);
            const bf16x8 Bh = hi_of(b0, b1);
            const bf16x8 Bl = lo_of(b0, b1);
            acc[c] = __builtin_amdgcn_mfma_f32_16x16x32_bf16(Ah, Bh, acc[c], 0, 0, 0);
            acc[c] = __builtin_amdgcn_mfma_f32_16x16x32_bf16(Ah, Bl, acc[c], 0, 0, 0);
            acc[c] = __builtin_amdgcn_mfma_f32_16x16x32_bf16(Al, Bh, acc[c], 0, 0, 0);
        }
    }
}

// ---------------- m-net residual kernel (MFMA, bf16 hi/lo split) ----------------
__global__ __launch_bounds__(BLK) void k_residual(
    const float* __restrict__ xtr,
    const float* __restrict__ mw0, const float* __restrict__ mb0,
    const float* __restrict__ mb1, const float* __restrict__ mb2,
    const float* __restrict__ mb3,
    const uint_t* __restrict__ wt1, const uint_t* __restrict__ wt2,
    const uint_t* __restrict__ w3t,
    const float* __restrict__ muArr, float* __restrict__ resPart) {
    __shared__ __align__(16) uint_t sW[128 * 132];    // 67,584 B (current layer, packed hi/lo)
    __shared__ __align__(16) uint_t sH[6 * 16 * 132]; // 50,688 B (6ch x 16pt x 128n packed)
    __shared__ __align__(16) uint_t sW3[16 * 132];    // 8,448 B
    __shared__ __align__(16) float sSm[772];          // W0 384 | b0 | b1 | b2 | b3(4)
    __shared__ __align__(16) float sO[6 * 16 * 4];    // final outputs [c][pt][k]
    __shared__ float sRed[NW][4];

    const int tid = threadIdx.x;
    const int lane = tid & 63;
    const int wv = tid >> 6;
    const int g = lane >> 4;    // lane group (k-group / row-group)
    const int l15 = lane & 15;  // point (B col) / A row within tile

    // prologue: stage W1, W3T, smalls
    {
        uint4* d4 = (uint4*)sW;
        const uint4* s4 = (const uint4*)wt1;
#pragma unroll
        for (int k = 0; k < 8; k++) d4[tid + k * BLK] = s4[tid + k * BLK];
        sW[16384 + tid] = wt1[16384 + tid];
        for (int i = tid; i < 16 * 132; i += BLK) sW3[i] = w3t[i];
        for (int i = tid; i < 384; i += BLK) sSm[i] = mw0[i];
        if (tid < 128) {
            sSm[384 + tid] = mb0[tid];
            sSm[512 + tid] = mb1[tid];
            sSm[640 + tid] = mb2[tid];
        }
        if (tid < 4) sSm[768 + tid] = mb3[tid];
    }
    __syncthreads();

    float racc[4] = {0.f, 0.f, 0.f, 0.f};
    const int base = blockIdx.x * 128;

    for (int b = 0; b < 8; b++) {
        const int pt0 = base + b * 16;

        // ---- layer 0: rows n = wv*16 + g*4 + r for point l15 ----
        {
            const int myp = pt0 + l15;
            const float x = xtr[myp * 3 + 0];
            const float y = xtr[myp * 3 + 1];
            const float t = xtr[myp * 3 + 2];
            uint_t wrd[6][4];
#pragma unroll
            for (int r = 0; r < 4; r++) {
                const int n = wv * 16 + g * 4 + r;
                const float wx = sSm[n], wy = sSm[128 + n], wz = sSm[256 + n];
                const float z = fmaf(wx, x, fmaf(wy, y, fmaf(wz, t, sSm[384 + n])));
                const float a = tanh_fast(z);
                const float s = 1.f - a * a;
                wrd[0][r] = pack_hl(a);
                wrd[1][r] = pack_hl(s * wx);
                wrd[2][r] = pack_hl(s * wy);
                wrd[3][r] = pack_hl(s * wz);
                wrd[4][r] = pack_hl(-2.f * a * s * wx * wx);
                wrd[5][r] = pack_hl(-2.f * a * s * wy * wy);
            }
#pragma unroll
            for (int c = 0; c < 6; c++)
                *(uint4*)&sH[c * 2112 + l15 * 132 + wv * 16 + g * 4] =
                    make_uint4(wrd[c][0], wrd[c][1], wrd[c][2], wrd[c][3]);
        }
        __syncthreads();  // B1

        // ---- layer 1 (W1 resident); prefetch W2 into regs meanwhile ----
        {
            uint4 pf[8]; uint_t pfx;
            const uint4* s4 = (const uint4*)wt2;
#pragma unroll
            for (int k = 0; k < 8; k++) pf[k] = s4[tid + k * BLK];
            pfx = wt2[16384 + tid];

            f32x4 acc[6];
#pragma unroll
            for (int c = 0; c < 6; c++) acc[c] = (f32x4){0.f, 0.f, 0.f, 0.f};
            mfma_layer(acc, sW, sH, wv, g, l15);

            uint_t wrd[6][4];
#pragma unroll
            for (int r = 0; r < 4; r++) {
                const int n = wv * 16 + g * 4 + r;
                const float zv = acc[0][r] + sSm[512 + n];
                const float a = tanh_fast(zv);
                const float s = 1.f - a * a;
                const float zx = acc[1][r], zy = acc[2][r];
                wrd[0][r] = pack_hl(a);
                wrd[1][r] = pack_hl(s * zx);
                wrd[2][r] = pack_hl(s * zy);
                wrd[3][r] = pack_hl(s * acc[3][r]);
                wrd[4][r] = pack_hl(s * acc[4][r] - 2.f * a * s * zx * zx);
                wrd[5][r] = pack_hl(s * acc[5][r] - 2.f * a * s * zy * zy);
            }
            __syncthreads();  // B2
            {
                uint4* d4 = (uint4*)sW;
#pragma unroll
                for (int k = 0; k < 8; k++) d4[tid + k * BLK] = pf[k];
                sW[16384 + tid] = pfx;
            }
#pragma unroll
            for (int c = 0; c < 6; c++)
                *(uint4*)&sH[c * 2112 + l15 * 132 + wv * 16 + g * 4] =
                    make_uint4(wrd[c][0], wrd[c][1], wrd[c][2], wrd[c][3]);
        }
        __syncthreads();  // B3

        // ---- layer 2 (W2 resident); prefetch W1 for next batch ----
        {
            uint4 pf[8]; uint_t pfx;
            const uint4* s4 = (const uint4*)wt1;
#pragma unroll
            for (int k = 0; k < 8; k++) pf[k] = s4[tid + k * BLK];
            pfx = wt1[16384 + tid];

            f32x4 acc[6];
#pragma unroll
            for (int c = 0; c < 6; c++) acc[c] = (f32x4){0.f, 0.f, 0.f, 0.f};
            mfma_layer(acc, sW, sH, wv, g, l15);

            uint_t wrd[6][4];
#pragma unroll
            for (int r = 0; r < 4; r++) {
                const int n = wv * 16 + g * 4 + r;
                const float zv = acc[0][r] + sSm[640 + n];
                const float a = tanh_fast(zv);
                const float s = 1.f - a * a;
                const float zx = acc[1][r], zy = acc[2][r];
                wrd[0][r] = pack_hl(a);
                wrd[1][r] = pack_hl(s * zx);
                wrd[2][r] = pack_hl(s * zy);
                wrd[3][r] = pack_hl(s * acc[3][r]);
                wrd[4][r] = pack_hl(s * acc[4][r] - 2.f * a * s * zx * zx);
                wrd[5][r] = pack_hl(s * acc[5][r] - 2.f * a * s * zy * zy);
            }
            __syncthreads();  // B4
            {
                uint4* d4 = (uint4*)sW;
#pragma unroll
                for (int k = 0; k < 8; k++) d4[tid + k * BLK] = pf[k];
                sW[16384 + tid] = pfx;
            }
#pragma unroll
            for (int c = 0; c < 6; c++)
                *(uint4*)&sH[c * 2112 + l15 * 132 + wv * 16 + g * 4] =
                    make_uint4(wrd[c][0], wrd[c][1], wrd[c][2], wrd[c][3]);
        }
        __syncthreads();  // B5

        // ---- final linear 128->4 for all 6 channels via MFMA (waves 0..5, c = wv) ----
        if (wv < 6) {
            const int c = wv;
            f32x4 a4 = (f32x4){0.f, 0.f, 0.f, 0.f};
#pragma unroll
            for (int ks = 0; ks < 4; ks++) {
                const uint_t* pa = &sW3[l15 * 132 + ks * 32 + g * 8];
                const uint4 a0 = *(const uint4*)pa;
                const uint4 a1 = *(const uint4*)(pa + 4);
                const bf16x8 Ah = hi_of(a0, a1);
                const bf16x8 Al = lo_of(a0, a1);
                const uint_t* pb = &sH[c * 2112 + l15 * 132 + ks * 32 + g * 8];
                const uint4 b0 = *(const uint4*)pb;
                const uint4 b1 = *(const uint4*)(pb + 4);
                const bf16x8 Bh = hi_of(b0, b1);
                const bf16x8 Bl = lo_of(b0, b1);
                a4 = __builtin_amdgcn_mfma_f32_16x16x32_bf16(Ah, Bh, a4, 0, 0, 0);
                a4 = __builtin_amdgcn_mfma_f32_16x16x32_bf16(Ah, Bl, a4, 0, 0, 0);
                a4 = __builtin_amdgcn_mfma_f32_16x16x32_bf16(Al, Bh, a4, 0, 0, 0);
            }
            if (g == 0) {  // rows 0..3 live in lanes 0..15, regs 0..3
                float4 o;
                o.x = a4[0]; o.y = a4[1]; o.z = a4[2]; o.w = a4[3];
                if (c == 0) { o.x += sSm[768]; o.y += sSm[769]; o.z += sSm[770]; o.w += sSm[771]; }
                *(float4*)&sO[c * 64 + l15 * 4] = o;
            }
        }
        __syncthreads();  // B6

        // ---- residual math: wave wv handles points 2wv, 2wv+1 (all lanes redundant) ----
#pragma unroll
        for (int pp = 0; pp < 2; pp++) {
            const int p = wv * 2 + pp;
            float oq[4][6];
#pragma unroll
            for (int k = 0; k < 4; k++)
#pragma unroll
                for (int c = 0; c < 6; c++) oq[k][c] = sO[c * 64 + p * 4 + k];

            const float rho = oq[0][0], rho_x = oq[0][1], rho_y = oq[0][2],
                        rho_t = oq[0][3], rho_xx = oq[0][4], rho_yy = oq[0][5];
            const float pr = oq[1][0], pr_x = oq[1][1], pr_y = oq[1][2],
                        pr_t = oq[1][3], pr_xx = oq[1][4], pr_yy = oq[1][5];
            const float u = oq[2][0], u_x = oq[2][1], u_y = oq[2][2],
                        u_t = oq[2][3], u_xx = oq[2][4], u_yy = oq[2][5];
            const float v = oq[3][0], v_x = oq[3][1], v_y = oq[3][2],
                        v_t = oq[3][3], v_xx = oq[3][4], v_yy = oq[3][5];

            const float ig1 = 2.5f;
            const float ke = 0.5f * (u * u + v * v);
            const float E = pr * ig1 + rho * ke;
            const float d_x = u * u_x + v * v_x;
            const float d_y = u * u_y + v * v_y;
            const float d_t = u * u_t + v * v_t;
            const float E_x = pr_x * ig1 + rho_x * ke + rho * d_x;
            const float E_y = pr_y * ig1 + rho_y * ke + rho * d_y;
            const float E_t = pr_t * ig1 + rho_t * ke + rho * d_t;
            const float E_xx = pr_xx * ig1 + rho_xx * ke + 2.f * rho_x * d_x +
                               rho * (u_x * u_x + u * u_xx + v_x * v_x + v * v_xx);
            const float E_yy = pr_yy * ig1 + rho_yy * ke + 2.f * rho_y * d_y +
                               rho * (u_y * u_y + u * u_yy + v_y * v_y + v * v_yy);

            const float m = muArr[pt0 + p];

            const float r1 = rho_t + (rho_x * u + rho * u_x) + (rho_y * v + rho * v_y)
                           - m * (rho_xx + rho_yy);
            const float r2 = (rho_t * u + rho * u_t)
                           + (rho_x * u * u + 2.f * rho * u * u_x + pr_x)
                           + (rho_y * u * v + rho * u_y * v + rho * u * v_y)
                           - m * ((rho_xx * u + 2.f * rho_x * u_x + rho * u_xx)
                                + (rho_yy * u + 2.f * rho_y * u_y + rho * u_yy));
            const float r3 = (rho_t * v + rho * v_t)
                           + (rho_x * u * v + rho * u_x * v + rho * u * v_x)
                           + (rho_y * v * v + 2.f * rho * v * v_y + pr_y)
                           - m * ((rho_xx * v + 2.f * rho_x * v_x + rho * v_xx)
                                + (rho_yy * v + 2.f * rho_y * v_y + rho * v_yy));
            const float r4 = E_t
                           + (u_x * (E + pr) + u * (E_x + pr_x))
                           + (v_y * (E + pr) + v * (E_y + pr_y))
                           - m * (E_xx + E_yy);

            racc[0] += r1 * r1;
            racc[1] += r2 * r2;
            racc[2] += r3 * r3;
            racc[3] += r4 * r4;
        }
    }

    if (lane == 0) {
        sRed[wv][0] = racc[0]; sRed[wv][1] = racc[1];
        sRed[wv][2] = racc[2]; sRed[wv][3] = racc[3];
    }
    __syncthreads();
    if (tid == 0) {
        float s0 = 0, s1 = 0, s2 = 0, s3 = 0;
#pragma unroll
        for (int w = 0; w < NW; w++) {
            s0 += sRed[w][0]; s1 += sRed[w][1]; s2 += sRed[w][2]; s3 += sRed[w][3];
        }
        resPart[blockIdx.x * 4 + 0] = s0;
        resPart[blockIdx.x * 4 + 1] = s1;
        resPart[blockIdx.x * 4 + 2] = s2;
        resPart[blockIdx.x * 4 + 3] = s3;
    }
}

// ======== round-1 fp32 helpers for k_mu / k_ic ========
__device__ __forceinline__ void stage_w(float* dst, const float* __restrict__ src, int tid) {
    const float4* s4 = (const float4*)src;
    float4* d4 = (float4*)dst;
#pragma unroll
    for (int k = 0; k < 8; k++) d4[tid + k * BLK] = s4[tid + k * BLK];
}

template <int NCH, int P>
__device__ __forceinline__ void layer0(const float* sSm, const float* __restrict__ xg,
                                       int ptg0, float* sHw, int lane) {
    const int n0 = lane * 2;
#pragma unroll
    for (int p = 0; p < P; p++) {
        const float x = xg[(ptg0 + p) * 3 + 0];
        const float y = xg[(ptg0 + p) * 3 + 1];
        const float t = xg[(ptg0 + p) * 3 + 2];
        float* hp = &sHw[p * NCH * HID];
#pragma unroll
        for (int tt = 0; tt < 2; tt++) {
            const int n = n0 + tt;
            const float wx = sSm[n], wy = sSm[HID + n], wz = sSm[2 * HID + n];
            const float z = sSm[3 * HID + n] + wx * x + wy * y + wz * t;
            hp[n] = tanh_fast(z);
        }
    }
}

template <int P>
__device__ __forceinline__ void hidden1(const float* sW, float* sHw, const float* sB, int lane) {
    const int n0 = lane * 2;
    float a0[P], a1[P];
#pragma unroll
    for (int p = 0; p < P; p++) { a0[p] = 0.f; a1[p] = 0.f; }
    for (int j = 0; j < HID; j += 4) {
        const float2 wa = *(const float2*)&sW[(j + 0) * HID + n0];
        const float2 wb = *(const float2*)&sW[(j + 1) * HID + n0];
        const float2 wc = *(const float2*)&sW[(j + 2) * HID + n0];
        const float2 wd = *(const float2*)&sW[(j + 3) * HID + n0];
#pragma unroll
        for (int p = 0; p < P; p++) {
            const float4 h = *(const float4*)&sHw[p * HID + j];
            a0[p] = fmaf(wa.x, h.x, fmaf(wb.x, h.y, fmaf(wc.x, h.z, fmaf(wd.x, h.w, a0[p]))));
            a1[p] = fmaf(wa.y, h.x, fmaf(wb.y, h.y, fmaf(wc.y, h.z, fmaf(wd.y, h.w, a1[p]))));
        }
    }
    const float b0v = sB[n0], b1v = sB[n0 + 1];
#pragma unroll
    for (int p = 0; p < P; p++) {
        *(float2*)&sHw[p * HID + n0] =
            make_float2(tanh_fast(a0[p] + b0v), tanh_fast(a1[p] + b1v));
    }
}

// ---------------- n-net: mu = 0.01*n(x)^2, plus sum(mu^2) partials ----------------
__global__ __launch_bounds__(BLK) void k_mu(
    const float* __restrict__ xtr,
    const float* __restrict__ nw0, const float* __restrict__ nb0,
    const float* __restrict__ nw1, const float* __restrict__ nb1,
    const float* __restrict__ nw2, const float* __restrict__ nb2,
    const float* __restrict__ nw3, const float* __restrict__ nb3,
    float* __restrict__ muArr, float* __restrict__ muPart) {
    __shared__ __align__(16) float sW[HID * HID];
    __shared__ __align__(16) float sH[64 * HID];
    __shared__ __align__(16) float sSm[897];
    __shared__ float sRed[8];

    const int tid = threadIdx.x;
    const int lane = tid & 63;
    const int wv = tid >> 6;

    for (int i = tid; i < 384; i += BLK) sSm[i] = nw0[i];
    for (int i = tid; i < HID; i += BLK) {
        sSm[384 + i] = nb0[i];
        sSm[512 + i] = nb1[i];
        sSm[640 + i] = nb2[i];
        sSm[768 + i] = nw3[i];
    }
    if (tid == 0) sSm[896] = nb3[0];
    __syncthreads();

    float accMu2 = 0.f;

    for (int it = blockIdx.x; it < NPTS / 64; it += GRID) {
        const int ptg0 = it * 64 + wv * 8;
        float* sHw = &sH[(wv * 8) * HID];
        layer0<1, 8>(sSm, xtr, ptg0, sHw, lane);
        __syncthreads();
        stage_w(sW, nw1, tid);
        __syncthreads();
        hidden1<8>(sW, sHw, &sSm[512], lane);
        __syncthreads();
        stage_w(sW, nw2, tid);
        __syncthreads();
        hidden1<8>(sW, sHw, &sSm[640], lane);

#pragma unroll
        for (int p = 0; p < 8; p++) {
            float o = 0.f;
#pragma unroll
            for (int jj = 0; jj < 2; jj++) {
                const int j = lane + jj * 64;
                o = fmaf(sSm[768 + j], sHw[p * HID + j], o);
            }
            o = wave_allsum(o);
            o += sSm[896];
            const float muv = 0.01f * o * o;
            if (lane == 0) muArr[ptg0 + p] = muv;
            accMu2 += muv * muv;
        }
    }
    if (lane == 0) sRed[wv] = accMu2;
    __syncthreads();
    if (tid == 0) {
        float s = 0.f;
#pragma unroll
        for (int w = 0; w < 8; w++) s += sRed[w];
        muPart[blockIdx.x] = s;
    }
}

// ---------------- IC branch ----------------
__global__ __launch_bounds__(BLK) void k_ic(
    const float* __restrict__ xin,
    const float* __restrict__ mw0, const float* __restrict__ mb0,
    const float* __restrict__ mw1, const float* __restrict__ mb1,
    const float* __restrict__ mw2, const float* __restrict__ mb2,
    const float* __restrict__ mw3, const float* __restrict__ mb3,
    const float* __restrict__ icg, float* __restrict__ icPart) {
    __shared__ __align__(16) float sW[HID * HID];
    __shared__ __align__(16) float sH[64 * HID];
    __shared__ __align__(16) float sSm[1284];
    __shared__ float sTq[16];
    __shared__ float sRed[8][8];

    const int tid = threadIdx.x;
    const int lane = tid & 63;
    const int wv = tid >> 6;

    for (int i = tid; i < 384; i += BLK) sSm[i] = mw0[i];
    for (int i = tid; i < HID; i += BLK) {
        sSm[384 + i] = mb0[i];
        sSm[512 + i] = mb1[i];
        sSm[640 + i] = mb2[i];
    }
    for (int i = tid; i < 512; i += BLK) sSm[768 + i] = mw3[i];
    if (tid < 4) sSm[1280 + tid] = mb3[tid];
    if (tid < 16) {
        const int k = tid & 3, q = tid >> 2;
        const int row = (q == 0) ? 1 : ((q == 1) ? 3 : ((q == 2) ? 0 : 2));
        const int pc = (k == 0) ? 0 : ((k == 1) ? 3 : ((k == 2) ? 1 : 2));
        sTq[q * 4 + k] = icg[row * 4 + pc];
    }
    __syncthreads();

    float qs[4] = {0, 0, 0, 0}, qc[4] = {0, 0, 0, 0};

    for (int it = blockIdx.x; it < NIC / 64; it += GRID) {
        const int ptg0 = it * 64 + wv * 8;
        float* sHw = &sH[(wv * 8) * HID];
        layer0<1, 8>(sSm, xin, ptg0, sHw, lane);
        __syncthreads();
        stage_w(sW, mw1, tid);
        __syncthreads();
        hidden1<8>(sW, sHw, &sSm[512], lane);
        __syncthreads();
        stage_w(sW, mw2, tid);
        __syncthreads();
        hidden1<8>(sW, sHw, &sSm[640], lane);

#pragma unroll
        for (int p = 0; p < 8; p++) {
            float o0 = 0, o1 = 0, o2 = 0, o3 = 0;
#pragma unroll
            for (int jj = 0; jj < 2; jj++) {
                const int j = lane + jj * 64;
                const float4 w3 = *(const float4*)&sSm[768 + j * 4];
                const float h = sHw[p * HID + j];
                o0 = fmaf(w3.x, h, o0);
                o1 = fmaf(w3.y, h, o1);
                o2 = fmaf(w3.z, h, o2);
                o3 = fmaf(w3.w, h, o3);
            }
            o0 = wave_allsum(o0); o1 = wave_allsum(o1);
            o2 = wave_allsum(o2); o3 = wave_allsum(o3);
            o0 += sSm[1280]; o1 += sSm[1281]; o2 += sSm[1282]; o3 += sSm[1283];

            const float x = xin[(ptg0 + p) * 3 + 0];
            const float y = xin[(ptg0 + p) * 3 + 1];
            int quad = -1;
            if (x < 0.5f && y > 0.5f) quad = 0;
            else if (x > 0.5f && y > 0.5f) quad = 1;
            else if (x < 0.5f && y < 0.5f) quad = 2;
            else if (x > 0.5f && y < 0.5f) quad = 3;
            if (quad >= 0) {
                const float d0 = o0 - sTq[quad * 4 + 0];
                const float d1 = o1 - sTq[quad * 4 + 1];
                const float d2 = o2 - sTq[quad * 4 + 2];
                const float d3 = o3 - sTq[quad * 4 + 3];
                const float ss = d0 * d0 + d1 * d1 + d2 * d2 + d3 * d3;
#pragma unroll
                for (int q = 0; q < 4; q++) {
                    qs[q] += (quad == q) ? ss : 0.f;
                    qc[q] += (quad == q) ? 1.f : 0.f;
                }
            }
        }
    }

    if (lane == 0) {
#pragma unroll
        for (int q = 0; q < 4; q++) { sRed[wv][q] = qs[q]; sRed[wv][4 + q] = qc[q]; }
    }
    __syncthreads();
    if (tid == 0) {
        float s[8] = {0, 0, 0, 0, 0, 0, 0, 0};
#pragma unroll
        for (int w = 0; w < 8; w++)
#pragma unroll
            for (int q = 0; q < 8; q++) s[q] += sRed[w][q];
#pragma unroll
        for (int q = 0; q < 8; q++) icPart[blockIdx.x * 8 + q] = s[q];
    }
}

// ---------------- finalize ----------------
__global__ void k_fin(const float* __restrict__ resPart, const float* __restrict__ muPart,
                      const float* __restrict__ icPart, float* __restrict__ out) {
    const int lane = threadIdx.x;
    float r[4] = {0, 0, 0, 0};
    float m2 = 0.f;
    float qs[4] = {0, 0, 0, 0}, qc[4] = {0, 0, 0, 0};
    for (int b = lane; b < GRID; b += 64) {
#pragma unroll
        for (int i = 0; i < 4; i++) r[i] += resPart[b * 4 + i];
        m2 += muPart[b];
#pragma unroll
        for (int q = 0; q < 4; q++) {
            qs[q] += icPart[b * 8 + q];
            qc[q] += icPart[b * 8 + 4 + q];
        }
    }
#pragma unroll
    for (int i = 0; i < 4; i++) r[i] = wave_allsum(r[i]);
    m2 = wave_allsum(m2);
#pragma unroll
    for (int q = 0; q < 4; q++) { qs[q] = wave_allsum(qs[q]); qc[q] = wave_allsum(qc[q]); }
    if (lane == 0) {
        const float sumr = (r[0] + r[1] + r[2] + r[3]) / (float)NPTS;
        float init_loss = 0.f;
#pragma unroll
        for (int q = 0; q < 4; q++) init_loss += qs[q] / fmaxf(qc[q], 1.f);
        out[0] = sumr + 10.f * init_loss + 0.1f * (m2 / (float)NPTS);
    }
}

extern "C" void kernel_launch(void* const* d_in, const int* in_sizes, int n_in,
                              void* d_out, int out_size, void* d_ws, size_t ws_size,
                              hipStream_t stream) {
    const float* xtr = (const float*)d_in[0];
    const float* xin = (const float*)d_in[1];
    const float* icg = (const float*)d_in[2];
    const float* mw0 = (const float*)d_in[3];
    const float* mb0 = (const float*)d_in[4];
    const float* mw1 = (const float*)d_in[5];
    const float* mb1 = (const float*)d_in[6];
    const float* mw2 = (const float*)d_in[7];
    const float* mb2 = (const float*)d_in[8];
    const float* mw3 = (const float*)d_in[9];
    const float* mb3 = (const float*)d_in[10];
    const float* nw0 = (const float*)d_in[11];
    const float* nb0 = (const float*)d_in[12];
    const float* nw1 = (const float*)d_in[13];
    const float* nb1 = (const float*)d_in[14];
    const float* nw2 = (const float*)d_in[15];
    const float* nb2 = (const float*)d_in[16];
    const float* nw3 = (const float*)d_in[17];
    const float* nb3 = (const float*)d_in[18];

    float* wsf = (float*)d_ws;
    float* muArr = wsf;                    // 32768 f
    float* resPart = wsf + 32768;          // 1024 f
    float* muPart = wsf + 33792;           // 256 f
    float* icPart = wsf + 34048;           // 2048 f
    uint_t* wt1 = (uint_t*)(wsf + 36096);  // 16896 words
    uint_t* wt2 = wt1 + 16896;             // 16896 words
    uint_t* w3t = wt2 + 16896;             // 2112 words  (total ws: 288,000 B)

    k_prep<<<2, BLK, 0, stream>>>(mw1, mw2, mw3, wt1, wt2, w3t);
    k_mu<<<GRID, BLK, 0, stream>>>(xtr, nw0, nb0, nw1, nb1, nw2, nb2, nw3, nb3,
                                   muArr, muPart);
    k_ic<<<GRID, BLK, 0, stream>>>(xin, mw0, mb0, mw1, mb1, mw2, mb2, mw3, mb3,
                                   icg, icPart);
    k_residual<<<GRID, BLK, 0, stream>>>(xtr, mw0, mb0, mb1, mb2, mb3,
                                         wt1, wt2, w3t, muArr, resPart);
    k_fin<<<1, 64, 0, stream>>>(resPart, muPart, icPart, (float*)d_out);
}

// Round 4
// 89.998 us; speedup vs baseline: 4.7809x; 2.5215x over previous
//
#include <hip/hip_runtime.h>

#define HID 128
#define NPTS 32768
#define NIC  16384
#define GRID 256
#define BLK  512
#define NW   8

typedef __attribute__((ext_vector_type(8))) _Float16 f16x8;
typedef __attribute__((ext_vector_type(4))) float f32x4;

// element-index XOR swizzle keyed on LDS row: spreads stride-256B rows over all banks
#define SWZ(e, r) ((e) ^ (((r) & 7) << 3))

__device__ __forceinline__ float tanh_fast(float x) {
    float e = __expf(2.0f * x);
    return 1.0f - 2.0f / (e + 1.0f);
}

__device__ __forceinline__ float wave_allsum(float v) {
#pragma unroll
    for (int off = 32; off > 0; off >>= 1) v += __shfl_xor(v, off, 64);
    return v;
}

__device__ __forceinline__ unsigned short f2hb(float x) {
    return __builtin_bit_cast(unsigned short, (_Float16)x);
}
__device__ __forceinline__ uint2 pack4h(float a, float b, float c, float d) {
    return make_uint2((unsigned)f2hb(a) | ((unsigned)f2hb(b) << 16),
                      (unsigned)f2hb(c) | ((unsigned)f2hb(d) << 16));
}

// ---------------- prep: transpose + fp16 hi/lo split + swizzle into ws ----------------
// plane[n*128 + SWZ(j, n)] = fp16(W[j][n]); lo plane = fp16(W - hi).
__global__ __launch_bounds__(BLK) void k_prep(
    const float* __restrict__ mw1, const float* __restrict__ mw2,
    const float* __restrict__ nw1, const float* __restrict__ nw2,
    const float* __restrict__ mw3,
    unsigned short* __restrict__ pk, unsigned short* __restrict__ w3t) {
    const int tid = threadIdx.x;
    const int bk = blockIdx.x;
    if (bk == 4) {
        for (int i = tid; i < 2048; i += BLK) w3t[i] = 0;
        __syncthreads();
        if (tid < 512) {
            const int j = tid & 127, k = tid >> 7;
            w3t[k * 128 + SWZ(j, k)] = f2hb(mw3[j * 4 + k]);
        }
        return;
    }
    const float* src = (bk == 0) ? mw1 : (bk == 1) ? mw2 : (bk == 2) ? nw1 : nw2;
    unsigned short* hi = pk + bk * 32768;
    unsigned short* lo = hi + 16384;
    __shared__ float sM[128 * 129];  // padded transpose buffer
#pragma unroll
    for (int k = 0; k < 32; k++) {
        const int idx = tid + k * BLK;
        const int j = idx >> 7, n = idx & 127;
        sM[n * 129 + j] = src[idx];
    }
    __syncthreads();
#pragma unroll
    for (int k = 0; k < 32; k++) {
        const int d = tid + k * BLK;
        const int n = d >> 7, js = d & 127;
        const int j = js ^ ((n & 7) << 3);
        const float w = sM[n * 129 + j];
        const _Float16 h = (_Float16)w;
        hi[d] = __builtin_bit_cast(unsigned short, h);
        lo[d] = f2hb(w - (float)h);
    }
}

// ---------------- m-net residual kernel: fp16 MFMA, both W resident ----------------
__global__ __launch_bounds__(BLK) void k_residual(
    const float* __restrict__ xtr,
    const float* __restrict__ mw0, const float* __restrict__ mb0,
    const float* __restrict__ mb1, const float* __restrict__ mb2,
    const float* __restrict__ mb3,
    const unsigned short* __restrict__ mpk, const unsigned short* __restrict__ w3t,
    const float* __restrict__ muArr, float* __restrict__ resPart) {
    __shared__ __align__(16) _Float16 sW[4 * 16384];  // W1h W1l W2h W2l  131072 B
    __shared__ __align__(16) _Float16 sH[6 * 2048];   // 6ch x 16pt x 128  24576 B
    __shared__ __align__(16) _Float16 sW3[2048];      // 16x128 (rows 0-3) 4096 B
    __shared__ float sB[260];                         // b1 | b2 | b3
    __shared__ float sO[384];                         // [c][pt][k]
    __shared__ float sRed[NW][4];

    const int tid = threadIdx.x;
    const int lane = tid & 63;
    const int wv = tid >> 6;
    const int g = lane >> 4;
    const int l15 = lane & 15;

    {
        const uint4* s4 = (const uint4*)mpk;
        uint4* d4 = (uint4*)sW;
#pragma unroll
        for (int k = 0; k < 16; k++) d4[tid + k * BLK] = s4[tid + k * BLK];
        if (tid < 256) ((uint4*)sW3)[tid] = ((const uint4*)w3t)[tid];
        if (tid < 128) { sB[tid] = mb1[tid]; sB[128 + tid] = mb2[tid]; }
        if (tid < 4) sB[256 + tid] = mb3[tid];
    }
    // layer-0 weight rows live in registers (fixed per lane)
    float w0x[4], w0y[4], w0z[4], w0b[4];
#pragma unroll
    for (int r = 0; r < 4; r++) {
        const int n = wv * 16 + g * 4 + r;
        w0x[r] = mw0[n]; w0y[r] = mw0[128 + n]; w0z[r] = mw0[256 + n]; w0b[r] = mb0[n];
    }
    __syncthreads();

    float racc[4] = {0.f, 0.f, 0.f, 0.f};
    const int base = blockIdx.x * 128;
    const int arow = wv * 16 + l15;  // A-fragment row (arow&7 == l15&7)
    const int hb = l15 * 128;        // B-fragment H row base

    for (int b = 0; b < 8; b++) {
        const int pt0 = base + b * 16;

        // ---- layer 0 ----
        {
            const int myp = pt0 + l15;
            const float x = xtr[myp * 3 + 0];
            const float y = xtr[myp * 3 + 1];
            const float t = xtr[myp * 3 + 2];
            float ch[6][4];
#pragma unroll
            for (int r = 0; r < 4; r++) {
                const float z = fmaf(w0x[r], x, fmaf(w0y[r], y, fmaf(w0z[r], t, w0b[r])));
                const float a = tanh_fast(z);
                const float s = 1.f - a * a;
                ch[0][r] = a;
                ch[1][r] = s * w0x[r];
                ch[2][r] = s * w0y[r];
                ch[3][r] = s * w0z[r];
                ch[4][r] = -2.f * a * s * w0x[r] * w0x[r];
                ch[5][r] = -2.f * a * s * w0y[r] * w0y[r];
            }
            const int e0 = SWZ(wv * 16 + g * 4, l15);
#pragma unroll
            for (int c = 0; c < 6; c++)
                *(uint2*)&sH[c * 2048 + hb + e0] =
                    pack4h(ch[c][0], ch[c][1], ch[c][2], ch[c][3]);
        }
        __syncthreads();

        // ---- two hidden layers, W1/W2 both resident ----
#pragma unroll
        for (int L = 0; L < 2; L++) {
            const _Float16* Wh = sW + (L * 2) * 16384;
            const _Float16* Wl = Wh + 16384;
            f32x4 acc[6];
#pragma unroll
            for (int c = 0; c < 6; c++) acc[c] = (f32x4){0.f, 0.f, 0.f, 0.f};
#pragma unroll
            for (int ks = 0; ks < 4; ks++) {
                const int ee = SWZ(ks * 32 + g * 8, l15);
                const f16x8 Ah = *(const f16x8*)&Wh[arow * 128 + ee];
                const f16x8 Al = *(const f16x8*)&Wl[arow * 128 + ee];
#pragma unroll
                for (int c = 0; c < 6; c++) {
                    const f16x8 Bv = *(const f16x8*)&sH[c * 2048 + hb + ee];
                    acc[c] = __builtin_amdgcn_mfma_f32_16x16x32_f16(Ah, Bv, acc[c], 0, 0, 0);
                    acc[c] = __builtin_amdgcn_mfma_f32_16x16x32_f16(Al, Bv, acc[c], 0, 0, 0);
                }
            }
            float ch[6][4];
#pragma unroll
            for (int r = 0; r < 4; r++) {
                const int n = wv * 16 + g * 4 + r;
                const float zv = acc[0][r] + sB[L * 128 + n];
                const float a = tanh_fast(zv);
                const float s = 1.f - a * a;
                const float zx = acc[1][r], zy = acc[2][r];
                ch[0][r] = a;
                ch[1][r] = s * zx;
                ch[2][r] = s * zy;
                ch[3][r] = s * acc[3][r];
                ch[4][r] = s * acc[4][r] - 2.f * a * s * zx * zx;
                ch[5][r] = s * acc[5][r] - 2.f * a * s * zy * zy;
            }
            __syncthreads();  // all H reads complete
            const int e0 = SWZ(wv * 16 + g * 4, l15);
#pragma unroll
            for (int c = 0; c < 6; c++)
                *(uint2*)&sH[c * 2048 + hb + e0] =
                    pack4h(ch[c][0], ch[c][1], ch[c][2], ch[c][3]);
            __syncthreads();
        }

        // ---- final linear 128->4, all 6 channels (waves 0..5) ----
        if (wv < 6) {
            f32x4 a4 = (f32x4){0.f, 0.f, 0.f, 0.f};
#pragma unroll
            for (int ks = 0; ks < 4; ks++) {
                const int ee = SWZ(ks * 32 + g * 8, l15);
                const f16x8 Ah = *(const f16x8*)&sW3[l15 * 128 + ee];
                const f16x8 Bv = *(const f16x8*)&sH[wv * 2048 + hb + ee];
                a4 = __builtin_amdgcn_mfma_f32_16x16x32_f16(Ah, Bv, a4, 0, 0, 0);
            }
            if (g == 0) {  // rows 0..3 -> lanes 0..15, regs 0..3
                float4 o;
                o.x = a4[0]; o.y = a4[1]; o.z = a4[2]; o.w = a4[3];
                if (wv == 0) { o.x += sB[256]; o.y += sB[257]; o.z += sB[258]; o.w += sB[259]; }
                *(float4*)&sO[wv * 64 + l15 * 4] = o;
            }
        }
        __syncthreads();

        // ---- residual math: wave wv handles points 2wv, 2wv+1 ----
#pragma unroll
        for (int pp = 0; pp < 2; pp++) {
            const int p = wv * 2 + pp;
            float oq[4][6];
#pragma unroll
            for (int k = 0; k < 4; k++)
#pragma unroll
                for (int c = 0; c < 6; c++) oq[k][c] = sO[c * 64 + p * 4 + k];

            const float rho = oq[0][0], rho_x = oq[0][1], rho_y = oq[0][2],
                        rho_t = oq[0][3], rho_xx = oq[0][4], rho_yy = oq[0][5];
            const float pr = oq[1][0], pr_x = oq[1][1], pr_y = oq[1][2],
                        pr_t = oq[1][3], pr_xx = oq[1][4], pr_yy = oq[1][5];
            const float u = oq[2][0], u_x = oq[2][1], u_y = oq[2][2],
                        u_t = oq[2][3], u_xx = oq[2][4], u_yy = oq[2][5];
            const float v = oq[3][0], v_x = oq[3][1], v_y = oq[3][2],
                        v_t = oq[3][3], v_xx = oq[3][4], v_yy = oq[3][5];

            const float ig1 = 2.5f;
            const float ke = 0.5f * (u * u + v * v);
            const float E = pr * ig1 + rho * ke;
            const float d_x = u * u_x + v * v_x;
            const float d_y = u * u_y + v * v_y;
            const float d_t = u * u_t + v * v_t;
            const float E_x = pr_x * ig1 + rho_x * ke + rho * d_x;
            const float E_y = pr_y * ig1 + rho_y * ke + rho * d_y;
            const float E_t = pr_t * ig1 + rho_t * ke + rho * d_t;
            const float E_xx = pr_xx * ig1 + rho_xx * ke + 2.f * rho_x * d_x +
                               rho * (u_x * u_x + u * u_xx + v_x * v_x + v * v_xx);
            const float E_yy = pr_yy * ig1 + rho_yy * ke + 2.f * rho_y * d_y +
                               rho * (u_y * u_y + u * u_yy + v_y * v_y + v * v_yy);

            const float m = muArr[pt0 + p];

            const float r1 = rho_t + (rho_x * u + rho * u_x) + (rho_y * v + rho * v_y)
                           - m * (rho_xx + rho_yy);
            const float r2 = (rho_t * u + rho * u_t)
                           + (rho_x * u * u + 2.f * rho * u * u_x + pr_x)
                           + (rho_y * u * v + rho * u_y * v + rho * u * v_y)
                           - m * ((rho_xx * u + 2.f * rho_x * u_x + rho * u_xx)
                                + (rho_yy * u + 2.f * rho_y * u_y + rho * u_yy));
            const float r3 = (rho_t * v + rho * v_t)
                           + (rho_x * u * v + rho * u_x * v + rho * u * v_x)
                           + (rho_y * v * v + 2.f * rho * v * v_y + pr_y)
                           - m * ((rho_xx * v + 2.f * rho_x * v_x + rho * v_xx)
                                + (rho_yy * v + 2.f * rho_y * v_y + rho * v_yy));
            const float r4 = E_t
                           + (u_x * (E + pr) + u * (E_x + pr_x))
                           + (v_y * (E + pr) + v * (E_y + pr_y))
                           - m * (E_xx + E_yy);

            racc[0] += r1 * r1;
            racc[1] += r2 * r2;
            racc[2] += r3 * r3;
            racc[3] += r4 * r4;
        }
    }

    if (lane == 0) {
        sRed[wv][0] = racc[0]; sRed[wv][1] = racc[1];
        sRed[wv][2] = racc[2]; sRed[wv][3] = racc[3];
    }
    __syncthreads();
    if (tid == 0) {
        float s0 = 0, s1 = 0, s2 = 0, s3 = 0;
#pragma unroll
        for (int w = 0; w < NW; w++) {
            s0 += sRed[w][0]; s1 += sRed[w][1]; s2 += sRed[w][2]; s3 += sRed[w][3];
        }
        resPart[blockIdx.x * 4 + 0] = s0;
        resPart[blockIdx.x * 4 + 1] = s1;
        resPart[blockIdx.x * 4 + 2] = s2;
        resPart[blockIdx.x * 4 + 3] = s3;
    }
}

// ---------------- n-net: mu = 0.01*n(x)^2 (fp16 MFMA, 64-pt batches) ----------------
__global__ __launch_bounds__(BLK) void k_mu(
    const float* __restrict__ xtr,
    const float* __restrict__ nw0, const float* __restrict__ nb0,
    const float* __restrict__ nb1, const float* __restrict__ nb2,
    const float* __restrict__ nw3, const float* __restrict__ nb3,
    const unsigned short* __restrict__ npk,
    float* __restrict__ muArr, float* __restrict__ muPart) {
    __shared__ __align__(16) _Float16 sW[4 * 16384];
    __shared__ __align__(16) _Float16 sH[64 * 128];
    __shared__ float sV[128];
    __shared__ float sB[257];
    __shared__ float sRed[NW];

    const int tid = threadIdx.x;
    const int lane = tid & 63;
    const int wv = tid >> 6;
    const int g = lane >> 4;
    const int l15 = lane & 15;

    {
        const uint4* s4 = (const uint4*)npk;
        uint4* d4 = (uint4*)sW;
#pragma unroll
        for (int k = 0; k < 16; k++) d4[tid + k * BLK] = s4[tid + k * BLK];
        if (tid < 128) { sV[tid] = nw3[tid]; sB[tid] = nb1[tid]; }
        else if (tid < 256) sB[tid] = nb2[tid - 128];
        if (tid == 256) sB[256] = nb3[0];
    }
    float w0x[4], w0y[4], w0z[4], w0b[4];
#pragma unroll
    for (int r = 0; r < 4; r++) {
        const int n = wv * 16 + g * 4 + r;
        w0x[r] = nw0[n]; w0y[r] = nw0[128 + n]; w0z[r] = nw0[256 + n]; w0b[r] = nb0[n];
    }
    __syncthreads();

    float accMu2 = 0.f;
    const int arow = wv * 16 + l15;

    for (int bt = 0; bt < 2; bt++) {
        const int pt0 = blockIdx.x * 128 + bt * 64;
        // layer 0 (4 point-tiles)
#pragma unroll
        for (int pt = 0; pt < 4; pt++) {
            const int lp = pt * 16 + l15;
            const int p = pt0 + lp;
            const float x = xtr[p * 3 + 0], y = xtr[p * 3 + 1], t = xtr[p * 3 + 2];
            float hv[4];
#pragma unroll
            for (int r = 0; r < 4; r++) {
                const float z = fmaf(w0x[r], x, fmaf(w0y[r], y, fmaf(w0z[r], t, w0b[r])));
                hv[r] = tanh_fast(z);
            }
            *(uint2*)&sH[lp * 128 + SWZ(wv * 16 + g * 4, lp)] =
                pack4h(hv[0], hv[1], hv[2], hv[3]);
        }
        __syncthreads();
#pragma unroll
        for (int L = 0; L < 2; L++) {
            const _Float16* Wh = sW + (L * 2) * 16384;
            const _Float16* Wl = Wh + 16384;
            f32x4 acc[4];
#pragma unroll
            for (int pt = 0; pt < 4; pt++) acc[pt] = (f32x4){0.f, 0.f, 0.f, 0.f};
#pragma unroll
            for (int ks = 0; ks < 4; ks++) {
                const int ee = SWZ(ks * 32 + g * 8, l15);
                const f16x8 Ah = *(const f16x8*)&Wh[arow * 128 + ee];
                const f16x8 Al = *(const f16x8*)&Wl[arow * 128 + ee];
#pragma unroll
                for (int pt = 0; pt < 4; pt++) {
                    const f16x8 Bv = *(const f16x8*)&sH[(pt * 16 + l15) * 128 + ee];
                    acc[pt] = __builtin_amdgcn_mfma_f32_16x16x32_f16(Ah, Bv, acc[pt], 0, 0, 0);
                    acc[pt] = __builtin_amdgcn_mfma_f32_16x16x32_f16(Al, Bv, acc[pt], 0, 0, 0);
                }
            }
            float hv[4][4];
#pragma unroll
            for (int pt = 0; pt < 4; pt++)
#pragma unroll
                for (int r = 0; r < 4; r++) {
                    const int n = wv * 16 + g * 4 + r;
                    hv[pt][r] = tanh_fast(acc[pt][r] + sB[L * 128 + n]);
                }
            __syncthreads();
#pragma unroll
            for (int pt = 0; pt < 4; pt++) {
                const int lp = pt * 16 + l15;
                *(uint2*)&sH[lp * 128 + SWZ(wv * 16 + g * 4, lp)] =
                    pack4h(hv[pt][0], hv[pt][1], hv[pt][2], hv[pt][3]);
            }
            __syncthreads();
        }
        // final dot: wave wv handles local points wv*8 .. wv*8+7
#pragma unroll
        for (int q = 0; q < 8; q++) {
            const int lp = wv * 8 + q;
            const float h1 = (float)sH[lp * 128 + SWZ(lane, lp)];
            const float h2 = (float)sH[lp * 128 + SWZ(64 + lane, lp)];
            float o = fmaf(h1, sV[lane], h2 * sV[64 + lane]);
            o = wave_allsum(o) + sB[256];
            const float muv = 0.01f * o * o;
            if (lane == 0) muArr[pt0 + lp] = muv;
            accMu2 += muv * muv;  // identical across lanes
        }
        __syncthreads();  // before next batch overwrites sH
    }
    if (lane == 0) sRed[wv] = accMu2;
    __syncthreads();
    if (tid == 0) {
        float s = 0.f;
#pragma unroll
        for (int w = 0; w < NW; w++) s += sRed[w];
        muPart[blockIdx.x] = s;
    }
}

// ---------------- IC branch: m-net value-only on x_initial (fp16 MFMA) ----------------
__global__ __launch_bounds__(BLK) void k_ic(
    const float* __restrict__ xin,
    const float* __restrict__ mw0, const float* __restrict__ mb0,
    const float* __restrict__ mb1, const float* __restrict__ mb2,
    const float* __restrict__ mw3, const float* __restrict__ mb3,
    const unsigned short* __restrict__ mpk,
    const float* __restrict__ icg, float* __restrict__ icPart) {
    __shared__ __align__(16) _Float16 sW[4 * 16384];
    __shared__ __align__(16) _Float16 sH[64 * 128];
    __shared__ float sW3v[512];  // [k][j] transposed
    __shared__ float sB[260];
    __shared__ float sTq[16];
    __shared__ float sRed[NW][8];

    const int tid = threadIdx.x;
    const int lane = tid & 63;
    const int wv = tid >> 6;
    const int g = lane >> 4;
    const int l15 = lane & 15;

    {
        const uint4* s4 = (const uint4*)mpk;
        uint4* d4 = (uint4*)sW;
#pragma unroll
        for (int k = 0; k < 16; k++) d4[tid + k * BLK] = s4[tid + k * BLK];
        {
            const int k = tid >> 7, j = tid & 127;
            sW3v[k * 128 + j] = mw3[j * 4 + k];  // 512 threads exactly
        }
        if (tid < 128) { sB[tid] = mb1[tid]; sB[128 + tid] = mb2[tid]; }
        if (tid < 4) sB[256 + tid] = mb3[tid];
        if (tid < 16) {
            const int k = tid & 3, q = tid >> 2;
            const int row = (q == 0) ? 1 : ((q == 1) ? 3 : ((q == 2) ? 0 : 2));
            const int pc = (k == 0) ? 0 : ((k == 1) ? 3 : ((k == 2) ? 1 : 2));
            sTq[q * 4 + k] = icg[row * 4 + pc];
        }
    }
    float w0x[4], w0y[4], w0z[4], w0b[4];
#pragma unroll
    for (int r = 0; r < 4; r++) {
        const int n = wv * 16 + g * 4 + r;
        w0x[r] = mw0[n]; w0y[r] = mw0[128 + n]; w0z[r] = mw0[256 + n]; w0b[r] = mb0[n];
    }
    __syncthreads();

    const int pt0 = blockIdx.x * 64;
    const int arow = wv * 16 + l15;

    // layer 0
#pragma unroll
    for (int pt = 0; pt < 4; pt++) {
        const int lp = pt * 16 + l15;
        const int p = pt0 + lp;
        const float x = xin[p * 3 + 0], y = xin[p * 3 + 1], t = xin[p * 3 + 2];
        float hv[4];
#pragma unroll
        for (int r = 0; r < 4; r++) {
            const float z = fmaf(w0x[r], x, fmaf(w0y[r], y, fmaf(w0z[r], t, w0b[r])));
            hv[r] = tanh_fast(z);
        }
        *(uint2*)&sH[lp * 128 + SWZ(wv * 16 + g * 4, lp)] = pack4h(hv[0], hv[1], hv[2], hv[3]);
    }
    __syncthreads();
#pragma unroll
    for (int L = 0; L < 2; L++) {
        const _Float16* Wh = sW + (L * 2) * 16384;
        const _Float16* Wl = Wh + 16384;
        f32x4 acc[4];
#pragma unroll
        for (int pt = 0; pt < 4; pt++) acc[pt] = (f32x4){0.f, 0.f, 0.f, 0.f};
#pragma unroll
        for (int ks = 0; ks < 4; ks++) {
            const int ee = SWZ(ks * 32 + g * 8, l15);
            const f16x8 Ah = *(const f16x8*)&Wh[arow * 128 + ee];
            const f16x8 Al = *(const f16x8*)&Wl[arow * 128 + ee];
#pragma unroll
            for (int pt = 0; pt < 4; pt++) {
                const f16x8 Bv = *(const f16x8*)&sH[(pt * 16 + l15) * 128 + ee];
                acc[pt] = __builtin_amdgcn_mfma_f32_16x16x32_f16(Ah, Bv, acc[pt], 0, 0, 0);
                acc[pt] = __builtin_amdgcn_mfma_f32_16x16x32_f16(Al, Bv, acc[pt], 0, 0, 0);
            }
        }
        float hv[4][4];
#pragma unroll
        for (int pt = 0; pt < 4; pt++)
#pragma unroll
            for (int r = 0; r < 4; r++) {
                const int n = wv * 16 + g * 4 + r;
                hv[pt][r] = tanh_fast(acc[pt][r] + sB[L * 128 + n]);
            }
        __syncthreads();
#pragma unroll
        for (int pt = 0; pt < 4; pt++) {
            const int lp = pt * 16 + l15;
            *(uint2*)&sH[lp * 128 + SWZ(wv * 16 + g * 4, lp)] =
                pack4h(hv[pt][0], hv[pt][1], hv[pt][2], hv[pt][3]);
        }
        __syncthreads();
    }

    // final 128->4 + quadrant loss: wave wv handles local points wv*8..+7
    float qs[4] = {0, 0, 0, 0}, qc[4] = {0, 0, 0, 0};
#pragma unroll
    for (int q = 0; q < 8; q++) {
        const int lp = wv * 8 + q;
        const int p = pt0 + lp;
        const float h1 = (float)sH[lp * 128 + SWZ(lane, lp)];
        const float h2 = (float)sH[lp * 128 + SWZ(64 + lane, lp)];
        float o0 = fmaf(h1, sW3v[lane], h2 * sW3v[64 + lane]);
        float o1 = fmaf(h1, sW3v[128 + lane], h2 * sW3v[192 + lane]);
        float o2 = fmaf(h1, sW3v[256 + lane], h2 * sW3v[320 + lane]);
        float o3 = fmaf(h1, sW3v[384 + lane], h2 * sW3v[448 + lane]);
        o0 = wave_allsum(o0) + sB[256];
        o1 = wave_allsum(o1) + sB[257];
        o2 = wave_allsum(o2) + sB[258];
        o3 = wave_allsum(o3) + sB[259];

        const float x = xin[p * 3 + 0];
        const float y = xin[p * 3 + 1];
        int quad = -1;
        if (x < 0.5f && y > 0.5f) quad = 0;
        else if (x > 0.5f && y > 0.5f) quad = 1;
        else if (x < 0.5f && y < 0.5f) quad = 2;
        else if (x > 0.5f && y < 0.5f) quad = 3;
        if (quad >= 0) {
            const float d0 = o0 - sTq[quad * 4 + 0];
            const float d1 = o1 - sTq[quad * 4 + 1];
            const float d2 = o2 - sTq[quad * 4 + 2];
            const float d3 = o3 - sTq[quad * 4 + 3];
            const float ss = d0 * d0 + d1 * d1 + d2 * d2 + d3 * d3;
#pragma unroll
            for (int qq = 0; qq < 4; qq++) {
                qs[qq] += (quad == qq) ? ss : 0.f;
                qc[qq] += (quad == qq) ? 1.f : 0.f;
            }
        }
    }

    if (lane == 0) {
#pragma unroll
        for (int q = 0; q < 4; q++) { sRed[wv][q] = qs[q]; sRed[wv][4 + q] = qc[q]; }
    }
    __syncthreads();
    if (tid == 0) {
        float s[8] = {0, 0, 0, 0, 0, 0, 0, 0};
#pragma unroll
        for (int w = 0; w < NW; w++)
#pragma unroll
            for (int q = 0; q < 8; q++) s[q] += sRed[w][q];
#pragma unroll
        for (int q = 0; q < 8; q++) icPart[blockIdx.x * 8 + q] = s[q];
    }
}

// ---------------- finalize: deterministic fixed-order combine ----------------
__global__ void k_fin(const float* __restrict__ resPart, const float* __restrict__ muPart,
                      const float* __restrict__ icPart, float* __restrict__ out) {
    const int lane = threadIdx.x;
    float r[4] = {0, 0, 0, 0};
    float m2 = 0.f;
    float qs[4] = {0, 0, 0, 0}, qc[4] = {0, 0, 0, 0};
    for (int b = lane; b < GRID; b += 64) {
#pragma unroll
        for (int i = 0; i < 4; i++) r[i] += resPart[b * 4 + i];
        m2 += muPart[b];
#pragma unroll
        for (int q = 0; q < 4; q++) {
            qs[q] += icPart[b * 8 + q];
            qc[q] += icPart[b * 8 + 4 + q];
        }
    }
#pragma unroll
    for (int i = 0; i < 4; i++) r[i] = wave_allsum(r[i]);
    m2 = wave_allsum(m2);
#pragma unroll
    for (int q = 0; q < 4; q++) { qs[q] = wave_allsum(qs[q]); qc[q] = wave_allsum(qc[q]); }
    if (lane == 0) {
        const float sumr = (r[0] + r[1] + r[2] + r[3]) / (float)NPTS;
        float init_loss = 0.f;
#pragma unroll
        for (int q = 0; q < 4; q++) init_loss += qs[q] / fmaxf(qc[q], 1.f);
        out[0] = sumr + 10.f * init_loss + 0.1f * (m2 / (float)NPTS);
    }
}

extern "C" void kernel_launch(void* const* d_in, const int* in_sizes, int n_in,
                              void* d_out, int out_size, void* d_ws, size_t ws_size,
                              hipStream_t stream) {
    const float* xtr = (const float*)d_in[0];
    const float* xin = (const float*)d_in[1];
    const float* icg = (const float*)d_in[2];
    const float* mw0 = (const float*)d_in[3];
    const float* mb0 = (const float*)d_in[4];
    const float* mw1 = (const float*)d_in[5];
    const float* mb1 = (const float*)d_in[6];
    const float* mw2 = (const float*)d_in[7];
    const float* mb2 = (const float*)d_in[8];
    const float* mw3 = (const float*)d_in[9];
    const float* mb3 = (const float*)d_in[10];
    const float* nw0 = (const float*)d_in[11];
    const float* nb0 = (const float*)d_in[12];
    const float* nw1 = (const float*)d_in[13];
    const float* nb1 = (const float*)d_in[14];
    const float* nw2 = (const float*)d_in[15];
    const float* nb2 = (const float*)d_in[16];
    const float* nw3 = (const float*)d_in[17];
    const float* nb3 = (const float*)d_in[18];

    float* wsf = (float*)d_ws;
    float* muArr = wsf;                                  // 32768 f
    float* resPart = wsf + 32768;                        // 1024 f
    float* muPart = wsf + 33792;                         // 256 f
    float* icPart = wsf + 34048;                         // 2048 f
    unsigned short* pk = (unsigned short*)(wsf + 36096); // 8 planes x 16384 u16
    unsigned short* mpk = pk;                            // m1h m1l m2h m2l
    unsigned short* npk = pk + 4 * 16384;                // n1h n1l n2h n2l
    unsigned short* w3t = pk + 8 * 16384;                // 2048 u16

    k_prep<<<5, BLK, 0, stream>>>(mw1, mw2, nw1, nw2, mw3, pk, w3t);
    k_mu<<<GRID, BLK, 0, stream>>>(xtr, nw0, nb0, nb1, nb2, nw3, nb3, npk,
                                   muArr, muPart);
    k_ic<<<GRID, BLK, 0, stream>>>(xin, mw0, mb0, mb1, mb2, mw3, mb3, mpk,
                                   icg, icPart);
    k_residual<<<GRID, BLK, 0, stream>>>(xtr, mw0, mb0, mb1, mb2, mb3,
                                         mpk, w3t, muArr, resPart);
    k_fin<<<1, 64, 0, stream>>>(resPart, muPart, icPart, (float*)d_out);
}

// Round 5
// 68.689 us; speedup vs baseline: 6.2640x; 1.3102x over previous
//
#include <hip/hip_runtime.h>

#define NPTS 32768
#define NIC  16384
#define GRID 256
#define GRID_MU 512
#define BLK  512
#define NW   8

typedef __attribute__((ext_vector_type(8))) _Float16 f16x8;
typedef __attribute__((ext_vector_type(4))) float f32x4;

// element-index XOR swizzle keyed on LDS row (row stride = 128 f16 = 256 B)
#define SWZ(e, r) ((e) ^ (((r) & 7) << 3))
#define MFMA16 __builtin_amdgcn_mfma_f32_16x16x32_f16

__device__ __forceinline__ float tanh_fast(float x) {
    float e = __expf(2.0f * x);
    return 1.0f - 2.0f / (e + 1.0f);
}

__device__ __forceinline__ float wave_allsum(float v) {
#pragma unroll
    for (int off = 32; off > 0; off >>= 1) v += __shfl_xor(v, off, 64);
    return v;
}

__device__ __forceinline__ unsigned short f2hb(float x) {
    return __builtin_bit_cast(unsigned short, (_Float16)x);
}
__device__ __forceinline__ uint2 pack4h(float a, float b, float c, float d) {
    return make_uint2((unsigned)f2hb(a) | ((unsigned)f2hb(b) << 16),
                      (unsigned)f2hb(c) | ((unsigned)f2hb(d) << 16));
}

// ---------------- prep: transpose + fp16 + swizzle: wt[n*128 + SWZ(j,n)] = f16(W[j][n]) ----------------
__global__ __launch_bounds__(BLK) void k_prep(
    const float* __restrict__ mw1, const float* __restrict__ mw2,
    const float* __restrict__ nw1, const float* __restrict__ nw2,
    const float* __restrict__ mw3,
    unsigned short* __restrict__ wt1, unsigned short* __restrict__ wt2,
    unsigned short* __restrict__ nt1, unsigned short* __restrict__ nt2,
    unsigned short* __restrict__ w3t) {
    const int tid = threadIdx.x;
    const int bk = blockIdx.x;
    if (bk == 4) {
        for (int i = tid; i < 2048; i += BLK) w3t[i] = 0;
        __syncthreads();
        if (tid < 512) {
            const int j = tid & 127, k = tid >> 7;
            w3t[k * 128 + SWZ(j, k)] = f2hb(mw3[j * 4 + k]);
        }
        return;
    }
    const float* src = (bk == 0) ? mw1 : (bk == 1) ? mw2 : (bk == 2) ? nw1 : nw2;
    unsigned short* dst = (bk == 0) ? wt1 : (bk == 1) ? wt2 : (bk == 2) ? nt1 : nt2;
    __shared__ float sM[128 * 129];
#pragma unroll
    for (int k = 0; k < 32; k++) {
        const int idx = tid + k * BLK;
        const int j = idx >> 7, n = idx & 127;
        sM[n * 129 + j] = src[idx];
    }
    __syncthreads();
#pragma unroll
    for (int k = 0; k < 32; k++) {
        const int d = tid + k * BLK;
        const int n = d >> 7, js = d & 127;
        const int j = js ^ ((n & 7) << 3);
        dst[d] = f2hb(sM[n * 129 + j]);
    }
}

// ---------------- m-net residual: 32-pt batches, 2rt x 6ch register blocking ----------------
__global__ __launch_bounds__(BLK) void k_residual(
    const float* __restrict__ xtr,
    const float* __restrict__ mw0, const float* __restrict__ mb0,
    const float* __restrict__ mb1, const float* __restrict__ mb2,
    const float* __restrict__ mb3,
    const unsigned short* __restrict__ wt1, const unsigned short* __restrict__ wt2,
    const unsigned short* __restrict__ w3t,
    const float* __restrict__ muArr, float* __restrict__ resPart) {
    __shared__ __align__(16) _Float16 sW1[16384];   // 32 KB
    __shared__ __align__(16) _Float16 sW2[16384];   // 32 KB
    __shared__ __align__(16) _Float16 sW3[2048];    // 4 KB (rows 4-15 zero)
    __shared__ __align__(16) _Float16 sH[6 * 4096]; // 48 KB: [ch][pt(32)][n(128)]
    __shared__ __align__(16) float sO[6 * 32 * 4];  // [ch][pt][k]
    __shared__ float sB[260];                       // b1 | b2 | b3

    const int tid = threadIdx.x;
    const int lane = tid & 63, wv = tid >> 6;
    const int g = lane >> 4, l15 = lane & 15;
    const int rtp = wv >> 1;             // row-tile pair: rows [rtp*32, rtp*32+32)
    const int ptile = wv & 1;            // point half-tile
    const int bp = ptile * 16 + l15;     // MFMA B row (local point)
    const int p32 = tid & 31;            // L0 / residual local point
    const int chunk = tid >> 5;          // L0 n-chunk

    {
        const uint4* s4 = (const uint4*)wt1;
        uint4* d4 = (uint4*)sW1;
#pragma unroll
        for (int k = 0; k < 4; k++) d4[tid + k * BLK] = s4[tid + k * BLK];
        s4 = (const uint4*)wt2; d4 = (uint4*)sW2;
#pragma unroll
        for (int k = 0; k < 4; k++) d4[tid + k * BLK] = s4[tid + k * BLK];
        if (tid < 256) ((uint4*)sW3)[tid] = ((const uint4*)w3t)[tid];
        if (tid < 128) { sB[tid] = mb1[tid]; sB[128 + tid] = mb2[tid]; }
        if (tid < 4) sB[256 + tid] = mb3[tid];
    }
    // layer-0 weight rows pinned in registers (reused all batches)
    float wxr[8], wyr[8], wzr[8], wbr[8];
#pragma unroll
    for (int j = 0; j < 8; j++) {
        const int n = chunk * 8 + j;
        wxr[j] = mw0[n]; wyr[j] = mw0[128 + n]; wzr[j] = mw0[256 + n]; wbr[j] = mb0[n];
    }
    __syncthreads();

    float racc0 = 0.f, racc1 = 0.f, racc2 = 0.f, racc3 = 0.f;
    const int base = blockIdx.x * 128;

    for (int b = 0; b < 4; b++) {
        const int pt0 = base + b * 32;

        // ---- layer 0: thread = (pt, 8-n chunk) ----
        {
            const int p = pt0 + p32;
            const float x = xtr[p * 3 + 0], y = xtr[p * 3 + 1], t = xtr[p * 3 + 2];
            float ch[6][8];
#pragma unroll
            for (int j = 0; j < 8; j++) {
                const float z = fmaf(wxr[j], x, fmaf(wyr[j], y, fmaf(wzr[j], t, wbr[j])));
                const float a = tanh_fast(z);
                const float s = 1.f - a * a;
                ch[0][j] = a;
                ch[1][j] = s * wxr[j];
                ch[2][j] = s * wyr[j];
                ch[3][j] = s * wzr[j];
                ch[4][j] = -2.f * a * s * wxr[j] * wxr[j];
                ch[5][j] = -2.f * a * s * wyr[j] * wyr[j];
            }
            const int off = p32 * 128 + SWZ(chunk * 8, p32);
#pragma unroll
            for (int c = 0; c < 6; c++) {
                const uint2 lo = pack4h(ch[c][0], ch[c][1], ch[c][2], ch[c][3]);
                const uint2 hi = pack4h(ch[c][4], ch[c][5], ch[c][6], ch[c][7]);
                *(uint4*)&sH[c * 4096 + off] = make_uint4(lo.x, lo.y, hi.x, hi.y);
            }
        }
        __syncthreads();

        // ---- two hidden layers ----
#pragma unroll
        for (int L = 0; L < 2; L++) {
            const _Float16* W = (L == 0) ? sW1 : sW2;
            f32x4 acc[2][6];
#pragma unroll
            for (int rr = 0; rr < 2; rr++)
#pragma unroll
                for (int c = 0; c < 6; c++) acc[rr][c] = (f32x4){0.f, 0.f, 0.f, 0.f};
#pragma unroll
            for (int ks = 0; ks < 4; ks++) {
                const int ee = SWZ(ks * 32 + g * 8, l15);
                const f16x8 A0 = *(const f16x8*)&W[(rtp * 32 + l15) * 128 + ee];
                const f16x8 A1 = *(const f16x8*)&W[(rtp * 32 + 16 + l15) * 128 + ee];
#pragma unroll
                for (int c = 0; c < 6; c++) {
                    const f16x8 Bv = *(const f16x8*)&sH[c * 4096 + bp * 128 + ee];
                    acc[0][c] = MFMA16(A0, Bv, acc[0][c], 0, 0, 0);
                    acc[1][c] = MFMA16(A1, Bv, acc[1][c], 0, 0, 0);
                }
            }
            float ch[2][6][4];
#pragma unroll
            for (int rr = 0; rr < 2; rr++)
#pragma unroll
                for (int r = 0; r < 4; r++) {
                    const int n = rtp * 32 + rr * 16 + g * 4 + r;
                    const float z0 = acc[rr][0][r] + sB[L * 128 + n];
                    const float a = tanh_fast(z0);
                    const float s = 1.f - a * a;
                    const float zx = acc[rr][1][r], zy = acc[rr][2][r];
                    ch[rr][0][r] = a;
                    ch[rr][1][r] = s * zx;
                    ch[rr][2][r] = s * zy;
                    ch[rr][3][r] = s * acc[rr][3][r];
                    ch[rr][4][r] = s * acc[rr][4][r] - 2.f * a * s * zx * zx;
                    ch[rr][5][r] = s * acc[rr][5][r] - 2.f * a * s * zy * zy;
                }
            __syncthreads();  // all H reads complete
#pragma unroll
            for (int rr = 0; rr < 2; rr++) {
                const int eo = bp * 128 + SWZ(rtp * 32 + rr * 16 + g * 4, bp);
#pragma unroll
                for (int c = 0; c < 6; c++)
                    *(uint2*)&sH[c * 4096 + eo] =
                        pack4h(ch[rr][c][0], ch[rr][c][1], ch[rr][c][2], ch[rr][c][3]);
            }
            __syncthreads();
        }

        // ---- final 128->4, 6 channels x 2 pt-tiles = 12 MFMA tiles ----
#pragma unroll
        for (int tt = 0; tt < 2; tt++) {
            const int t = wv + tt * 8;
            if (t < 12) {
                const int c = t % 6, pti = t / 6;
                const int fp = pti * 16 + l15;
                f32x4 a4 = (f32x4){0.f, 0.f, 0.f, 0.f};
#pragma unroll
                for (int ks = 0; ks < 4; ks++) {
                    const int ee = SWZ(ks * 32 + g * 8, l15);
                    const f16x8 Af = *(const f16x8*)&sW3[l15 * 128 + ee];
                    const f16x8 Bf = *(const f16x8*)&sH[c * 4096 + fp * 128 + ee];
                    a4 = MFMA16(Af, Bf, a4, 0, 0, 0);
                }
                if (g == 0) {  // rows 0-3 -> lanes 0-15, regs 0-3
                    float4 o = make_float4(a4[0], a4[1], a4[2], a4[3]);
                    if (c == 0) { o.x += sB[256]; o.y += sB[257]; o.z += sB[258]; o.w += sB[259]; }
                    *(float4*)&sO[(c * 32 + fp) * 4] = o;
                }
            }
        }
        __syncthreads();

        // ---- residual math: thread handles pt = tid&31 (redundant x16; tid<32 accumulates) ----
        {
            const float m = muArr[pt0 + p32];
            float oq[4][6];
#pragma unroll
            for (int c = 0; c < 6; c++) {
                const float4 o = *(const float4*)&sO[(c * 32 + p32) * 4];
                oq[0][c] = o.x; oq[1][c] = o.y; oq[2][c] = o.z; oq[3][c] = o.w;
            }
            const float rho = oq[0][0], rho_x = oq[0][1], rho_y = oq[0][2],
                        rho_t = oq[0][3], rho_xx = oq[0][4], rho_yy = oq[0][5];
            const float pr = oq[1][0], pr_x = oq[1][1], pr_y = oq[1][2],
                        pr_t = oq[1][3], pr_xx = oq[1][4], pr_yy = oq[1][5];
            const float u = oq[2][0], u_x = oq[2][1], u_y = oq[2][2],
                        u_t = oq[2][3], u_xx = oq[2][4], u_yy = oq[2][5];
            const float v = oq[3][0], v_x = oq[3][1], v_y = oq[3][2],
                        v_t = oq[3][3], v_xx = oq[3][4], v_yy = oq[3][5];

            const float ig1 = 2.5f;
            const float ke = 0.5f * (u * u + v * v);
            const float E = pr * ig1 + rho * ke;
            const float d_x = u * u_x + v * v_x;
            const float d_y = u * u_y + v * v_y;
            const float d_t = u * u_t + v * v_t;
            const float E_x = pr_x * ig1 + rho_x * ke + rho * d_x;
            const float E_y = pr_y * ig1 + rho_y * ke + rho * d_y;
            const float E_t = pr_t * ig1 + rho_t * ke + rho * d_t;
            const float E_xx = pr_xx * ig1 + rho_xx * ke + 2.f * rho_x * d_x +
                               rho * (u_x * u_x + u * u_xx + v_x * v_x + v * v_xx);
            const float E_yy = pr_yy * ig1 + rho_yy * ke + 2.f * rho_y * d_y +
                               rho * (u_y * u_y + u * u_yy + v_y * v_y + v * v_yy);

            const float r1 = rho_t + (rho_x * u + rho * u_x) + (rho_y * v + rho * v_y)
                           - m * (rho_xx + rho_yy);
            const float r2 = (rho_t * u + rho * u_t)
                           + (rho_x * u * u + 2.f * rho * u * u_x + pr_x)
                           + (rho_y * u * v + rho * u_y * v + rho * u * v_y)
                           - m * ((rho_xx * u + 2.f * rho_x * u_x + rho * u_xx)
                                + (rho_yy * u + 2.f * rho_y * u_y + rho * u_yy));
            const float r3 = (rho_t * v + rho * v_t)
                           + (rho_x * u * v + rho * u_x * v + rho * u * v_x)
                           + (rho_y * v * v + 2.f * rho * v * v_y + pr_y)
                           - m * ((rho_xx * v + 2.f * rho_x * v_x + rho * v_xx)
                                + (rho_yy * v + 2.f * rho_y * v_y + rho * v_yy));
            const float r4 = E_t
                           + (u_x * (E + pr) + u * (E_x + pr_x))
                           + (v_y * (E + pr) + v * (E_y + pr_y))
                           - m * (E_xx + E_yy);
            if (tid < 32) {
                racc0 += r1 * r1; racc1 += r2 * r2;
                racc2 += r3 * r3; racc3 += r4 * r4;
            }
        }
    }

    if (wv == 0) {  // lanes 32-63 hold zeros
        racc0 = wave_allsum(racc0);
        racc1 = wave_allsum(racc1);
        racc2 = wave_allsum(racc2);
        racc3 = wave_allsum(racc3);
        if (lane == 0) {
            resPart[blockIdx.x * 4 + 0] = racc0;
            resPart[blockIdx.x * 4 + 1] = racc1;
            resPart[blockIdx.x * 4 + 2] = racc2;
            resPart[blockIdx.x * 4 + 3] = racc3;
        }
    }
}

// ---------------- n-net: mu = 0.01*n(x)^2; 64 pts/block, 512 blocks ----------------
__global__ __launch_bounds__(BLK) void k_mu(
    const float* __restrict__ xtr,
    const float* __restrict__ nw0, const float* __restrict__ nb0,
    const float* __restrict__ nb1, const float* __restrict__ nb2,
    const float* __restrict__ nw3, const float* __restrict__ nb3,
    const unsigned short* __restrict__ nt1, const unsigned short* __restrict__ nt2,
    float* __restrict__ muArr, float* __restrict__ muPart) {
    __shared__ __align__(16) _Float16 sW1[16384];
    __shared__ __align__(16) _Float16 sW2[16384];
    __shared__ __align__(16) _Float16 sH[4096];  // [pt(32)][n(128)]
    __shared__ float sV[128], sB[257];
    __shared__ float sRed[NW];

    const int tid = threadIdx.x;
    const int lane = tid & 63, wv = tid >> 6;
    const int g = lane >> 4, l15 = lane & 15;
    const int rtp = wv >> 1, ptile = wv & 1;
    const int bp = ptile * 16 + l15;
    const int p32 = tid & 31;
    const int chunk = tid >> 5;

    {
        const uint4* s4 = (const uint4*)nt1;
        uint4* d4 = (uint4*)sW1;
#pragma unroll
        for (int k = 0; k < 4; k++) d4[tid + k * BLK] = s4[tid + k * BLK];
        s4 = (const uint4*)nt2; d4 = (uint4*)sW2;
#pragma unroll
        for (int k = 0; k < 4; k++) d4[tid + k * BLK] = s4[tid + k * BLK];
        if (tid < 128) { sV[tid] = nw3[tid]; sB[tid] = nb1[tid]; }
        else if (tid < 256) sB[tid] = nb2[tid - 128];
        if (tid == 256) sB[256] = nb3[0];
    }
    float wxr[8], wyr[8], wzr[8], wbr[8];
#pragma unroll
    for (int j = 0; j < 8; j++) {
        const int n = chunk * 8 + j;
        wxr[j] = nw0[n]; wyr[j] = nw0[128 + n]; wzr[j] = nw0[256 + n]; wbr[j] = nb0[n];
    }
    __syncthreads();

    float accMu2 = 0.f;

    for (int b = 0; b < 2; b++) {
        const int pt0 = blockIdx.x * 64 + b * 32;
        {
            const int p = pt0 + p32;
            const float x = xtr[p * 3 + 0], y = xtr[p * 3 + 1], t = xtr[p * 3 + 2];
            float hv[8];
#pragma unroll
            for (int j = 0; j < 8; j++)
                hv[j] = tanh_fast(fmaf(wxr[j], x, fmaf(wyr[j], y, fmaf(wzr[j], t, wbr[j]))));
            const uint2 lo = pack4h(hv[0], hv[1], hv[2], hv[3]);
            const uint2 hi = pack4h(hv[4], hv[5], hv[6], hv[7]);
            *(uint4*)&sH[p32 * 128 + SWZ(chunk * 8, p32)] = make_uint4(lo.x, lo.y, hi.x, hi.y);
        }
        __syncthreads();
#pragma unroll
        for (int L = 0; L < 2; L++) {
            const _Float16* W = (L == 0) ? sW1 : sW2;
            f32x4 acc[2];
            acc[0] = (f32x4){0.f, 0.f, 0.f, 0.f};
            acc[1] = (f32x4){0.f, 0.f, 0.f, 0.f};
#pragma unroll
            for (int ks = 0; ks < 4; ks++) {
                const int ee = SWZ(ks * 32 + g * 8, l15);
                const f16x8 A0 = *(const f16x8*)&W[(rtp * 32 + l15) * 128 + ee];
                const f16x8 A1 = *(const f16x8*)&W[(rtp * 32 + 16 + l15) * 128 + ee];
                const f16x8 Bv = *(const f16x8*)&sH[bp * 128 + ee];
                acc[0] = MFMA16(A0, Bv, acc[0], 0, 0, 0);
                acc[1] = MFMA16(A1, Bv, acc[1], 0, 0, 0);
            }
            float hv[2][4];
#pragma unroll
            for (int rr = 0; rr < 2; rr++)
#pragma unroll
                for (int r = 0; r < 4; r++) {
                    const int n = rtp * 32 + rr * 16 + g * 4 + r;
                    hv[rr][r] = tanh_fast(acc[rr][r] + sB[L * 128 + n]);
                }
            __syncthreads();
#pragma unroll
            for (int rr = 0; rr < 2; rr++)
                *(uint2*)&sH[bp * 128 + SWZ(rtp * 32 + rr * 16 + g * 4, bp)] =
                    pack4h(hv[rr][0], hv[rr][1], hv[rr][2], hv[rr][3]);
            __syncthreads();
        }
        // final dot: wave wv handles local points wv*4 .. wv*4+3
#pragma unroll
        for (int q = 0; q < 4; q++) {
            const int lp = wv * 4 + q;
            const float h1 = (float)sH[lp * 128 + SWZ(lane, lp)];
            const float h2 = (float)sH[lp * 128 + SWZ(64 + lane, lp)];
            float o = fmaf(h1, sV[lane], h2 * sV[64 + lane]);
            o = wave_allsum(o) + sB[256];
            const float muv = 0.01f * o * o;
            if (lane == 0) muArr[pt0 + lp] = muv;
            accMu2 += muv * muv;  // lane-identical
        }
        __syncthreads();
    }
    if (lane == 0) sRed[wv] = accMu2;
    __syncthreads();
    if (tid == 0) {
        float s = 0.f;
#pragma unroll
        for (int w = 0; w < NW; w++) s += sRed[w];
        muPart[blockIdx.x] = s;
    }
}

// ---------------- IC branch: m-net value-only, 64 pts/block ----------------
__global__ __launch_bounds__(BLK) void k_ic(
    const float* __restrict__ xin,
    const float* __restrict__ mw0, const float* __restrict__ mb0,
    const float* __restrict__ mb1, const float* __restrict__ mb2,
    const float* __restrict__ mw3, const float* __restrict__ mb3,
    const unsigned short* __restrict__ wt1, const unsigned short* __restrict__ wt2,
    const float* __restrict__ icg, float* __restrict__ icPart) {
    __shared__ __align__(16) _Float16 sW1[16384];
    __shared__ __align__(16) _Float16 sW2[16384];
    __shared__ __align__(16) _Float16 sH[4096];
    __shared__ float sW3v[512];  // [k][j]
    __shared__ float sB[260];
    __shared__ float sTq[16];
    __shared__ float sRed[NW][8];

    const int tid = threadIdx.x;
    const int lane = tid & 63, wv = tid >> 6;
    const int g = lane >> 4, l15 = lane & 15;
    const int rtp = wv >> 1, ptile = wv & 1;
    const int bp = ptile * 16 + l15;
    const int p32 = tid & 31;
    const int chunk = tid >> 5;

    {
        const uint4* s4 = (const uint4*)wt1;
        uint4* d4 = (uint4*)sW1;
#pragma unroll
        for (int k = 0; k < 4; k++) d4[tid + k * BLK] = s4[tid + k * BLK];
        s4 = (const uint4*)wt2; d4 = (uint4*)sW2;
#pragma unroll
        for (int k = 0; k < 4; k++) d4[tid + k * BLK] = s4[tid + k * BLK];
        {
            const int k = tid >> 7, j = tid & 127;
            sW3v[k * 128 + j] = mw3[j * 4 + k];
        }
        if (tid < 128) { sB[tid] = mb1[tid]; sB[128 + tid] = mb2[tid]; }
        if (tid < 4) sB[256 + tid] = mb3[tid];
        if (tid < 16) {
            const int k = tid & 3, q = tid >> 2;
            const int row = (q == 0) ? 1 : ((q == 1) ? 3 : ((q == 2) ? 0 : 2));
            const int pc = (k == 0) ? 0 : ((k == 1) ? 3 : ((k == 2) ? 1 : 2));
            sTq[q * 4 + k] = icg[row * 4 + pc];
        }
    }
    float wxr[8], wyr[8], wzr[8], wbr[8];
#pragma unroll
    for (int j = 0; j < 8; j++) {
        const int n = chunk * 8 + j;
        wxr[j] = mw0[n]; wyr[j] = mw0[128 + n]; wzr[j] = mw0[256 + n]; wbr[j] = mb0[n];
    }
    __syncthreads();

    float qs[4] = {0, 0, 0, 0}, qc[4] = {0, 0, 0, 0};

    for (int b = 0; b < 2; b++) {
        const int pt0 = blockIdx.x * 64 + b * 32;
        {
            const int p = pt0 + p32;
            const float x = xin[p * 3 + 0], y = xin[p * 3 + 1], t = xin[p * 3 + 2];
            float hv[8];
#pragma unroll
            for (int j = 0; j < 8; j++)
                hv[j] = tanh_fast(fmaf(wxr[j], x, fmaf(wyr[j], y, fmaf(wzr[j], t, wbr[j]))));
            const uint2 lo = pack4h(hv[0], hv[1], hv[2], hv[3]);
            const uint2 hi = pack4h(hv[4], hv[5], hv[6], hv[7]);
            *(uint4*)&sH[p32 * 128 + SWZ(chunk * 8, p32)] = make_uint4(lo.x, lo.y, hi.x, hi.y);
        }
        __syncthreads();
#pragma unroll
        for (int L = 0; L < 2; L++) {
            const _Float16* W = (L == 0) ? sW1 : sW2;
            f32x4 acc[2];
            acc[0] = (f32x4){0.f, 0.f, 0.f, 0.f};
            acc[1] = (f32x4){0.f, 0.f, 0.f, 0.f};
#pragma unroll
            for (int ks = 0; ks < 4; ks++) {
                const int ee = SWZ(ks * 32 + g * 8, l15);
                const f16x8 A0 = *(const f16x8*)&W[(rtp * 32 + l15) * 128 + ee];
                const f16x8 A1 = *(const f16x8*)&W[(rtp * 32 + 16 + l15) * 128 + ee];
                const f16x8 Bv = *(const f16x8*)&sH[bp * 128 + ee];
                acc[0] = MFMA16(A0, Bv, acc[0], 0, 0, 0);
                acc[1] = MFMA16(A1, Bv, acc[1], 0, 0, 0);
            }
            float hv[2][4];
#pragma unroll
            for (int rr = 0; rr < 2; rr++)
#pragma unroll
                for (int r = 0; r < 4; r++) {
                    const int n = rtp * 32 + rr * 16 + g * 4 + r;
                    hv[rr][r] = tanh_fast(acc[rr][r] + sB[L * 128 + n]);
                }
            __syncthreads();
#pragma unroll
            for (int rr = 0; rr < 2; rr++)
                *(uint2*)&sH[bp * 128 + SWZ(rtp * 32 + rr * 16 + g * 4, bp)] =
                    pack4h(hv[rr][0], hv[rr][1], hv[rr][2], hv[rr][3]);
            __syncthreads();
        }
        // final 128->4 + quadrant loss: wave wv handles local points wv*4..+3
#pragma unroll
        for (int q = 0; q < 4; q++) {
            const int lp = wv * 4 + q;
            const int p = pt0 + lp;
            const float h1 = (float)sH[lp * 128 + SWZ(lane, lp)];
            const float h2 = (float)sH[lp * 128 + SWZ(64 + lane, lp)];
            float o0 = fmaf(h1, sW3v[lane], h2 * sW3v[64 + lane]);
            float o1 = fmaf(h1, sW3v[128 + lane], h2 * sW3v[192 + lane]);
            float o2 = fmaf(h1, sW3v[256 + lane], h2 * sW3v[320 + lane]);
            float o3 = fmaf(h1, sW3v[384 + lane], h2 * sW3v[448 + lane]);
            o0 = wave_allsum(o0) + sB[256];
            o1 = wave_allsum(o1) + sB[257];
            o2 = wave_allsum(o2) + sB[258];
            o3 = wave_allsum(o3) + sB[259];

            const float x = xin[p * 3 + 0];
            const float y = xin[p * 3 + 1];
            int quad = -1;
            if (x < 0.5f && y > 0.5f) quad = 0;
            else if (x > 0.5f && y > 0.5f) quad = 1;
            else if (x < 0.5f && y < 0.5f) quad = 2;
            else if (x > 0.5f && y < 0.5f) quad = 3;
            if (quad >= 0) {  // wave-uniform
                const float d0 = o0 - sTq[quad * 4 + 0];
                const float d1 = o1 - sTq[quad * 4 + 1];
                const float d2 = o2 - sTq[quad * 4 + 2];
                const float d3 = o3 - sTq[quad * 4 + 3];
                const float ss = d0 * d0 + d1 * d1 + d2 * d2 + d3 * d3;
#pragma unroll
                for (int qq = 0; qq < 4; qq++) {
                    qs[qq] += (quad == qq) ? ss : 0.f;
                    qc[qq] += (quad == qq) ? 1.f : 0.f;
                }
            }
        }
        __syncthreads();
    }

    if (lane == 0) {
#pragma unroll
        for (int q = 0; q < 4; q++) { sRed[wv][q] = qs[q]; sRed[wv][4 + q] = qc[q]; }
    }
    __syncthreads();
    if (tid == 0) {
        float s[8] = {0, 0, 0, 0, 0, 0, 0, 0};
#pragma unroll
        for (int w = 0; w < NW; w++)
#pragma unroll
            for (int q = 0; q < 8; q++) s[q] += sRed[w][q];
#pragma unroll
        for (int q = 0; q < 8; q++) icPart[blockIdx.x * 8 + q] = s[q];
    }
}

// ---------------- finalize ----------------
__global__ void k_fin(const float* __restrict__ resPart, const float* __restrict__ muPart,
                      const float* __restrict__ icPart, float* __restrict__ out) {
    const int lane = threadIdx.x;
    float r[4] = {0, 0, 0, 0};
    float m2 = 0.f;
    float qs[4] = {0, 0, 0, 0}, qc[4] = {0, 0, 0, 0};
    for (int b = lane; b < GRID; b += 64) {
#pragma unroll
        for (int i = 0; i < 4; i++) r[i] += resPart[b * 4 + i];
#pragma unroll
        for (int q = 0; q < 4; q++) {
            qs[q] += icPart[b * 8 + q];
            qc[q] += icPart[b * 8 + 4 + q];
        }
    }
    for (int b = lane; b < GRID_MU; b += 64) m2 += muPart[b];
#pragma unroll
    for (int i = 0; i < 4; i++) r[i] = wave_allsum(r[i]);
    m2 = wave_allsum(m2);
#pragma unroll
    for (int q = 0; q < 4; q++) { qs[q] = wave_allsum(qs[q]); qc[q] = wave_allsum(qc[q]); }
    if (lane == 0) {
        const float sumr = (r[0] + r[1] + r[2] + r[3]) / (float)NPTS;
        float init_loss = 0.f;
#pragma unroll
        for (int q = 0; q < 4; q++) init_loss += qs[q] / fmaxf(qc[q], 1.f);
        out[0] = sumr + 10.f * init_loss + 0.1f * (m2 / (float)NPTS);
    }
}

extern "C" void kernel_launch(void* const* d_in, const int* in_sizes, int n_in,
                              void* d_out, int out_size, void* d_ws, size_t ws_size,
                              hipStream_t stream) {
    const float* xtr = (const float*)d_in[0];
    const float* xin = (const float*)d_in[1];
    const float* icg = (const float*)d_in[2];
    const float* mw0 = (const float*)d_in[3];
    const float* mb0 = (const float*)d_in[4];
    const float* mw1 = (const float*)d_in[5];
    const float* mb1 = (const float*)d_in[6];
    const float* mw2 = (const float*)d_in[7];
    const float* mb2 = (const float*)d_in[8];
    const float* mw3 = (const float*)d_in[9];
    const float* mb3 = (const float*)d_in[10];
    const float* nw0 = (const float*)d_in[11];
    const float* nb0 = (const float*)d_in[12];
    const float* nw1 = (const float*)d_in[13];
    const float* nb1 = (const float*)d_in[14];
    const float* nw2 = (const float*)d_in[15];
    const float* nb2 = (const float*)d_in[16];
    const float* nw3 = (const float*)d_in[17];
    const float* nb3 = (const float*)d_in[18];

    float* wsf = (float*)d_ws;
    float* muArr = wsf;                                   // 32768 f
    float* resPart = wsf + 32768;                         // 1024 f
    float* muPart = wsf + 33792;                          // 512 f
    float* icPart = wsf + 34304;                          // 2048 f
    unsigned short* wt1 = (unsigned short*)(wsf + 36864); // 16384 u16
    unsigned short* wt2 = wt1 + 16384;
    unsigned short* nt1 = wt2 + 16384;
    unsigned short* nt2 = nt1 + 16384;
    unsigned short* w3t = nt2 + 16384;                    // 2048 u16

    k_prep<<<5, BLK, 0, stream>>>(mw1, mw2, nw1, nw2, mw3, wt1, wt2, nt1, nt2, w3t);
    k_mu<<<GRID_MU, BLK, 0, stream>>>(xtr, nw0, nb0, nb1, nb2, nw3, nb3, nt1, nt2,
                                      muArr, muPart);
    k_ic<<<GRID, BLK, 0, stream>>>(xin, mw0, mb0, mb1, mb2, mw3, mb3, wt1, wt2,
                                   icg, icPart);
    k_residual<<<GRID, BLK, 0, stream>>>(xtr, mw0, mb0, mb1, mb2, mb3,
                                         wt1, wt2, w3t, muArr, resPart);
    k_fin<<<1, 64, 0, stream>>>(resPart, muPart, icPart, (float*)d_out);
}

// Round 7
// 66.954 us; speedup vs baseline: 6.4263x; 1.0259x over previous
//
#include <hip/hip_runtime.h>

#define NPTS 32768
#define NIC  16384
#define GRID 256
#define BLK  512
#define NW   8

typedef __attribute__((ext_vector_type(8))) _Float16 f16x8;
typedef __attribute__((ext_vector_type(4))) float f32x4;

// element-index XOR swizzle keyed on LDS row (row stride = 128 f16 = 256 B)
#define SWZ(e, r) ((e) ^ (((r) & 7) << 3))
#define MFMA16 __builtin_amdgcn_mfma_f32_16x16x32_f16

__device__ __forceinline__ float tanh_fast(float x) {
    float e = __expf(2.0f * x);
    return 1.0f - 2.0f / (e + 1.0f);
}

__device__ __forceinline__ float wave_allsum(float v) {
#pragma unroll
    for (int off = 32; off > 0; off >>= 1) v += __shfl_xor(v, off, 64);
    return v;
}

__device__ __forceinline__ unsigned short f2hb(float x) {
    return __builtin_bit_cast(unsigned short, (_Float16)x);
}
__device__ __forceinline__ uint2 pack4h(float a, float b, float c, float d) {
    return make_uint2((unsigned)f2hb(a) | ((unsigned)f2hb(b) << 16),
                      (unsigned)f2hb(c) | ((unsigned)f2hb(d) << 16));
}

// ---------------- prep (round-5, proven): transpose + fp16 + swizzle ----------------
__global__ __launch_bounds__(BLK) void k_prep(
    const float* __restrict__ mw1, const float* __restrict__ mw2,
    const float* __restrict__ nw1, const float* __restrict__ nw2,
    const float* __restrict__ mw3,
    unsigned short* __restrict__ wt1, unsigned short* __restrict__ wt2,
    unsigned short* __restrict__ nt1, unsigned short* __restrict__ nt2,
    unsigned short* __restrict__ w3t) {
    const int tid = threadIdx.x;
    const int bk = blockIdx.x;
    if (bk == 4) {
        for (int i = tid; i < 2048; i += BLK) w3t[i] = 0;
        __syncthreads();
        if (tid < 512) {
            const int j = tid & 127, k = tid >> 7;
            w3t[k * 128 + SWZ(j, k)] = f2hb(mw3[j * 4 + k]);
        }
        return;
    }
    const float* src = (bk == 0) ? mw1 : (bk == 1) ? mw2 : (bk == 2) ? nw1 : nw2;
    unsigned short* dst = (bk == 0) ? wt1 : (bk == 1) ? wt2 : (bk == 2) ? nt1 : nt2;
    __shared__ float sM[128 * 129];
#pragma unroll
    for (int k = 0; k < 32; k++) {
        const int idx = tid + k * BLK;
        const int j = idx >> 7, n = idx & 127;
        sM[n * 129 + j] = src[idx];
    }
    __syncthreads();
#pragma unroll
    for (int k = 0; k < 32; k++) {
        const int d = tid + k * BLK;
        const int n = d >> 7, js = d & 127;
        const int j = js ^ ((n & 7) << 3);
        dst[d] = f2hb(sM[n * 129 + j]);
    }
}

// ================= fused kernel: stage-n | mu | stage-m | ic | residual =================
__global__ __launch_bounds__(BLK) void k_fused(
    const float* __restrict__ xtr, const float* __restrict__ xin,
    const float* __restrict__ icg,
    const float* __restrict__ mw0, const float* __restrict__ mb0,
    const float* __restrict__ mb1, const float* __restrict__ mb2,
    const float* __restrict__ mw3, const float* __restrict__ mb3,
    const float* __restrict__ nw0, const float* __restrict__ nb0,
    const float* __restrict__ nb1, const float* __restrict__ nb2,
    const float* __restrict__ nw3, const float* __restrict__ nb3,
    const unsigned short* __restrict__ wt1, const unsigned short* __restrict__ wt2,
    const unsigned short* __restrict__ nt1, const unsigned short* __restrict__ nt2,
    const unsigned short* __restrict__ w3t,
    float* __restrict__ resPart, float* __restrict__ muPart,
    float* __restrict__ icPart) {
    __shared__ __align__(16) _Float16 sW1[16384];    // 32 KB
    __shared__ __align__(16) _Float16 sW2[16384];    // 32 KB
    __shared__ __align__(16) _Float16 sH[6 * 4096];  // 48 KB
    __shared__ __align__(16) _Float16 sW3[2048];     // 4 KB
    __shared__ __align__(16) float sO[768];
    __shared__ float sB[520];   // mb1|mb2|mb3 @0/128/256 ; nb1|nb2|nb3 @260/388/516
    __shared__ float sV[128];
    __shared__ float sW3v[512];
    __shared__ float sMu[128];
    __shared__ float sTq[16];
    __shared__ float sRed[NW][8];

    const int tid = threadIdx.x;
    const int lane = tid & 63, wv = tid >> 6;
    const int g = lane >> 4, l15 = lane & 15;
    const int rtp = wv >> 1, ptile = wv & 1;
    const int bp = ptile * 16 + l15;
    const int p32 = tid & 31;
    const int chunk = tid >> 5;
    const int base = blockIdx.x * 128;

    // ---------- phase 0: stage n-net (linear copies, proven pattern) ----------
    {
        const uint4* s4 = (const uint4*)nt1;
        uint4* d4 = (uint4*)sW1;
#pragma unroll
        for (int k = 0; k < 4; k++) d4[tid + k * BLK] = s4[tid + k * BLK];
        s4 = (const uint4*)nt2; d4 = (uint4*)sW2;
#pragma unroll
        for (int k = 0; k < 4; k++) d4[tid + k * BLK] = s4[tid + k * BLK];
        if (tid < 128) {
            sV[tid] = nw3[tid];
            sB[260 + tid] = nb1[tid];
            sB[388 + tid] = nb2[tid];
        }
        if (tid == 0) sB[516] = nb3[0];
    }
    float wxr[8], wyr[8], wzr[8], wbr[8];
#pragma unroll
    for (int j = 0; j < 8; j++) {
        const int n = chunk * 8 + j;
        wxr[j] = nw0[n]; wyr[j] = nw0[128 + n]; wzr[j] = nw0[256 + n]; wbr[j] = nb0[n];
    }
    __syncthreads();

    // ---------- phase 1: mu over this block's 128 training points ----------
    float accMu2 = 0.f;
    for (int b = 0; b < 4; b++) {
        const int pt0 = base + b * 32;
        {
            const int p = pt0 + p32;
            const float x = xtr[p * 3 + 0], y = xtr[p * 3 + 1], t = xtr[p * 3 + 2];
            float hv[8];
#pragma unroll
            for (int j = 0; j < 8; j++)
                hv[j] = tanh_fast(fmaf(wxr[j], x, fmaf(wyr[j], y, fmaf(wzr[j], t, wbr[j]))));
            const uint2 lo = pack4h(hv[0], hv[1], hv[2], hv[3]);
            const uint2 hi = pack4h(hv[4], hv[5], hv[6], hv[7]);
            *(uint4*)&sH[p32 * 128 + SWZ(chunk * 8, p32)] = make_uint4(lo.x, lo.y, hi.x, hi.y);
        }
        __syncthreads();
#pragma unroll
        for (int L = 0; L < 2; L++) {
            const _Float16* W = (L == 0) ? sW1 : sW2;
            f32x4 a0 = (f32x4){0.f, 0.f, 0.f, 0.f};
            f32x4 a1 = (f32x4){0.f, 0.f, 0.f, 0.f};
#pragma unroll
            for (int ks = 0; ks < 4; ks++) {
                const int ee = SWZ(ks * 32 + g * 8, l15);
                const f16x8 A0 = *(const f16x8*)&W[(rtp * 32 + l15) * 128 + ee];
                const f16x8 A1 = *(const f16x8*)&W[(rtp * 32 + 16 + l15) * 128 + ee];
                const f16x8 Bv = *(const f16x8*)&sH[bp * 128 + ee];
                a0 = MFMA16(A0, Bv, a0, 0, 0, 0);
                a1 = MFMA16(A1, Bv, a1, 0, 0, 0);
            }
            float hv[2][4];
#pragma unroll
            for (int r = 0; r < 4; r++) {
                const int n0 = rtp * 32 + g * 4 + r;
                hv[0][r] = tanh_fast(a0[r] + sB[260 + L * 128 + n0]);
                hv[1][r] = tanh_fast(a1[r] + sB[260 + L * 128 + n0 + 16]);
            }
            __syncthreads();
#pragma unroll
            for (int rr = 0; rr < 2; rr++)
                *(uint2*)&sH[bp * 128 + SWZ(rtp * 32 + rr * 16 + g * 4, bp)] =
                    pack4h(hv[rr][0], hv[rr][1], hv[rr][2], hv[rr][3]);
            __syncthreads();
        }
#pragma unroll
        for (int q = 0; q < 4; q++) {
            const int lp = wv * 4 + q;
            const float h1 = (float)sH[lp * 128 + SWZ(lane, lp)];
            const float h2 = (float)sH[lp * 128 + SWZ(64 + lane, lp)];
            float o = fmaf(h1, sV[lane], h2 * sV[64 + lane]);
            o = wave_allsum(o) + sB[516];
            const float muv = 0.01f * o * o;
            if (lane == 0) sMu[b * 32 + lp] = muv;
            accMu2 += muv * muv;  // lane-identical
        }
        __syncthreads();
    }
    if (lane == 0) sRed[wv][0] = accMu2;
    __syncthreads();
    if (tid == 0) {
        float s = 0.f;
#pragma unroll
        for (int w = 0; w < NW; w++) s += sRed[w][0];
        muPart[blockIdx.x] = s;
    }
    __syncthreads();

    // ---------- phase 2: stage m-net (linear copies) ----------
    {
        const uint4* s4 = (const uint4*)wt1;
        uint4* d4 = (uint4*)sW1;
#pragma unroll
        for (int k = 0; k < 4; k++) d4[tid + k * BLK] = s4[tid + k * BLK];
        s4 = (const uint4*)wt2; d4 = (uint4*)sW2;
#pragma unroll
        for (int k = 0; k < 4; k++) d4[tid + k * BLK] = s4[tid + k * BLK];
        if (tid < 256) ((uint4*)sW3)[tid] = ((const uint4*)w3t)[tid];
        {
            const int k = tid >> 7, j = tid & 127;
            sW3v[k * 128 + j] = mw3[j * 4 + k];
        }
        if (tid < 128) { sB[tid] = mb1[tid]; sB[128 + tid] = mb2[tid]; }
        if (tid < 4) sB[256 + tid] = mb3[tid];
        if (tid < 16) {
            const int k = tid & 3, q = tid >> 2;
            const int row = (q == 0) ? 1 : ((q == 1) ? 3 : ((q == 2) ? 0 : 2));
            const int pc = (k == 0) ? 0 : ((k == 1) ? 3 : ((k == 2) ? 1 : 2));
            sTq[q * 4 + k] = icg[row * 4 + pc];
        }
    }
#pragma unroll
    for (int j = 0; j < 8; j++) {
        const int n = chunk * 8 + j;
        wxr[j] = mw0[n]; wyr[j] = mw0[128 + n]; wzr[j] = mw0[256 + n]; wbr[j] = mb0[n];
    }
    __syncthreads();

    // ---------- phase 3: IC on this block's 64 initial points ----------
    float qs[4] = {0, 0, 0, 0}, qc[4] = {0, 0, 0, 0};
    for (int b = 0; b < 2; b++) {
        const int pt0 = blockIdx.x * 64 + b * 32;
        {
            const int p = pt0 + p32;
            const float x = xin[p * 3 + 0], y = xin[p * 3 + 1], t = xin[p * 3 + 2];
            float hv[8];
#pragma unroll
            for (int j = 0; j < 8; j++)
                hv[j] = tanh_fast(fmaf(wxr[j], x, fmaf(wyr[j], y, fmaf(wzr[j], t, wbr[j]))));
            const uint2 lo = pack4h(hv[0], hv[1], hv[2], hv[3]);
            const uint2 hi = pack4h(hv[4], hv[5], hv[6], hv[7]);
            *(uint4*)&sH[p32 * 128 + SWZ(chunk * 8, p32)] = make_uint4(lo.x, lo.y, hi.x, hi.y);
        }
        __syncthreads();
#pragma unroll
        for (int L = 0; L < 2; L++) {
            const _Float16* W = (L == 0) ? sW1 : sW2;
            f32x4 a0 = (f32x4){0.f, 0.f, 0.f, 0.f};
            f32x4 a1 = (f32x4){0.f, 0.f, 0.f, 0.f};
#pragma unroll
            for (int ks = 0; ks < 4; ks++) {
                const int ee = SWZ(ks * 32 + g * 8, l15);
                const f16x8 A0 = *(const f16x8*)&W[(rtp * 32 + l15) * 128 + ee];
                const f16x8 A1 = *(const f16x8*)&W[(rtp * 32 + 16 + l15) * 128 + ee];
                const f16x8 Bv = *(const f16x8*)&sH[bp * 128 + ee];
                a0 = MFMA16(A0, Bv, a0, 0, 0, 0);
                a1 = MFMA16(A1, Bv, a1, 0, 0, 0);
            }
            float hv[2][4];
#pragma unroll
            for (int r = 0; r < 4; r++) {
                const int n0 = rtp * 32 + g * 4 + r;
                hv[0][r] = tanh_fast(a0[r] + sB[L * 128 + n0]);
                hv[1][r] = tanh_fast(a1[r] + sB[L * 128 + n0 + 16]);
            }
            __syncthreads();
#pragma unroll
            for (int rr = 0; rr < 2; rr++)
                *(uint2*)&sH[bp * 128 + SWZ(rtp * 32 + rr * 16 + g * 4, bp)] =
                    pack4h(hv[rr][0], hv[rr][1], hv[rr][2], hv[rr][3]);
            __syncthreads();
        }
#pragma unroll
        for (int q = 0; q < 4; q++) {
            const int lp = wv * 4 + q;
            const int p = pt0 + lp;
            const float h1 = (float)sH[lp * 128 + SWZ(lane, lp)];
            const float h2 = (float)sH[lp * 128 + SWZ(64 + lane, lp)];
            float o0 = fmaf(h1, sW3v[lane], h2 * sW3v[64 + lane]);
            float o1 = fmaf(h1, sW3v[128 + lane], h2 * sW3v[192 + lane]);
            float o2 = fmaf(h1, sW3v[256 + lane], h2 * sW3v[320 + lane]);
            float o3 = fmaf(h1, sW3v[384 + lane], h2 * sW3v[448 + lane]);
            o0 = wave_allsum(o0) + sB[256];
            o1 = wave_allsum(o1) + sB[257];
            o2 = wave_allsum(o2) + sB[258];
            o3 = wave_allsum(o3) + sB[259];

            const float x = xin[p * 3 + 0];
            const float y = xin[p * 3 + 1];
            int quad = -1;
            if (x < 0.5f && y > 0.5f) quad = 0;
            else if (x > 0.5f && y > 0.5f) quad = 1;
            else if (x < 0.5f && y < 0.5f) quad = 2;
            else if (x > 0.5f && y < 0.5f) quad = 3;
            if (quad >= 0) {  // wave-uniform
                const float d0 = o0 - sTq[quad * 4 + 0];
                const float d1 = o1 - sTq[quad * 4 + 1];
                const float d2 = o2 - sTq[quad * 4 + 2];
                const float d3 = o3 - sTq[quad * 4 + 3];
                const float ss = d0 * d0 + d1 * d1 + d2 * d2 + d3 * d3;
#pragma unroll
                for (int qq = 0; qq < 4; qq++) {
                    qs[qq] += (quad == qq) ? ss : 0.f;
                    qc[qq] += (quad == qq) ? 1.f : 0.f;
                }
            }
        }
        __syncthreads();
    }
    if (lane == 0) {
#pragma unroll
        for (int q = 0; q < 4; q++) { sRed[wv][q] = qs[q]; sRed[wv][4 + q] = qc[q]; }
    }
    __syncthreads();
    if (tid == 0) {
        float s[8] = {0, 0, 0, 0, 0, 0, 0, 0};
#pragma unroll
        for (int w = 0; w < NW; w++)
#pragma unroll
            for (int q = 0; q < 8; q++) s[q] += sRed[w][q];
#pragma unroll
        for (int q = 0; q < 8; q++) icPart[blockIdx.x * 8 + q] = s[q];
    }
    __syncthreads();

    // ---------- phase 4: residual over this block's 128 training points ----------
    float racc0 = 0.f, racc1 = 0.f, racc2 = 0.f, racc3 = 0.f;
    for (int b = 0; b < 4; b++) {
        const int pt0 = base + b * 32;

        // layer 0 (6 dual channels)
        {
            const int p = pt0 + p32;
            const float x = xtr[p * 3 + 0], y = xtr[p * 3 + 1], t = xtr[p * 3 + 2];
            float ch[6][8];
#pragma unroll
            for (int j = 0; j < 8; j++) {
                const float z = fmaf(wxr[j], x, fmaf(wyr[j], y, fmaf(wzr[j], t, wbr[j])));
                const float a = tanh_fast(z);
                const float s = 1.f - a * a;
                ch[0][j] = a;
                ch[1][j] = s * wxr[j];
                ch[2][j] = s * wyr[j];
                ch[3][j] = s * wzr[j];
                ch[4][j] = -2.f * a * s * wxr[j] * wxr[j];
                ch[5][j] = -2.f * a * s * wyr[j] * wyr[j];
            }
            const int off = p32 * 128 + SWZ(chunk * 8, p32);
#pragma unroll
            for (int c = 0; c < 6; c++) {
                const uint2 lo = pack4h(ch[c][0], ch[c][1], ch[c][2], ch[c][3]);
                const uint2 hi = pack4h(ch[c][4], ch[c][5], ch[c][6], ch[c][7]);
                *(uint4*)&sH[c * 4096 + off] = make_uint4(lo.x, lo.y, hi.x, hi.y);
            }
        }
        __syncthreads();

        // two hidden layers
#pragma unroll
        for (int L = 0; L < 2; L++) {
            const _Float16* W = (L == 0) ? sW1 : sW2;
            f32x4 acc[2][6];
#pragma unroll
            for (int rr = 0; rr < 2; rr++)
#pragma unroll
                for (int c = 0; c < 6; c++) acc[rr][c] = (f32x4){0.f, 0.f, 0.f, 0.f};
#pragma unroll
            for (int ks = 0; ks < 4; ks++) {
                const int ee = SWZ(ks * 32 + g * 8, l15);
                const f16x8 A0 = *(const f16x8*)&W[(rtp * 32 + l15) * 128 + ee];
                const f16x8 A1 = *(const f16x8*)&W[(rtp * 32 + 16 + l15) * 128 + ee];
#pragma unroll
                for (int c = 0; c < 6; c++) {
                    const f16x8 Bv = *(const f16x8*)&sH[c * 4096 + bp * 128 + ee];
                    acc[0][c] = MFMA16(A0, Bv, acc[0][c], 0, 0, 0);
                    acc[1][c] = MFMA16(A1, Bv, acc[1][c], 0, 0, 0);
                }
            }
            float ch[2][6][4];
#pragma unroll
            for (int rr = 0; rr < 2; rr++)
#pragma unroll
                for (int r = 0; r < 4; r++) {
                    const int n = rtp * 32 + rr * 16 + g * 4 + r;
                    const float z0 = acc[rr][0][r] + sB[L * 128 + n];
                    const float a = tanh_fast(z0);
                    const float s = 1.f - a * a;
                    const float zx = acc[rr][1][r], zy = acc[rr][2][r];
                    ch[rr][0][r] = a;
                    ch[rr][1][r] = s * zx;
                    ch[rr][2][r] = s * zy;
                    ch[rr][3][r] = s * acc[rr][3][r];
                    ch[rr][4][r] = s * acc[rr][4][r] - 2.f * a * s * zx * zx;
                    ch[rr][5][r] = s * acc[rr][5][r] - 2.f * a * s * zy * zy;
                }
            __syncthreads();
#pragma unroll
            for (int rr = 0; rr < 2; rr++) {
                const int eo = bp * 128 + SWZ(rtp * 32 + rr * 16 + g * 4, bp);
#pragma unroll
                for (int c = 0; c < 6; c++)
                    *(uint2*)&sH[c * 4096 + eo] =
                        pack4h(ch[rr][c][0], ch[rr][c][1], ch[rr][c][2], ch[rr][c][3]);
            }
            __syncthreads();
        }

        // final 128->4, 6 ch x 2 pt-tiles = 12 MFMA tiles
#pragma unroll
        for (int tt = 0; tt < 2; tt++) {
            const int t = wv + tt * 8;
            if (t < 12) {
                const int c = t % 6, pti = t / 6;
                const int fp = pti * 16 + l15;
                f32x4 a4 = (f32x4){0.f, 0.f, 0.f, 0.f};
#pragma unroll
                for (int ks = 0; ks < 4; ks++) {
                    const int ee = SWZ(ks * 32 + g * 8, l15);
                    const f16x8 Af = *(const f16x8*)&sW3[l15 * 128 + ee];
                    const f16x8 Bf = *(const f16x8*)&sH[c * 4096 + fp * 128 + ee];
                    a4 = MFMA16(Af, Bf, a4, 0, 0, 0);
                }
                if (g == 0) {
                    float4 o = make_float4(a4[0], a4[1], a4[2], a4[3]);
                    if (c == 0) { o.x += sB[256]; o.y += sB[257]; o.z += sB[258]; o.w += sB[259]; }
                    *(float4*)&sO[(c * 32 + fp) * 4] = o;
                }
            }
        }
        __syncthreads();

        // residual math (thread handles p32; tid<32 accumulate)
        {
            const float m = sMu[b * 32 + p32];
            float oq[4][6];
#pragma unroll
            for (int c = 0; c < 6; c++) {
                const float4 o = *(const float4*)&sO[(c * 32 + p32) * 4];
                oq[0][c] = o.x; oq[1][c] = o.y; oq[2][c] = o.z; oq[3][c] = o.w;
            }
            const float rho = oq[0][0], rho_x = oq[0][1], rho_y = oq[0][2],
                        rho_t = oq[0][3], rho_xx = oq[0][4], rho_yy = oq[0][5];
            const float pr = oq[1][0], pr_x = oq[1][1], pr_y = oq[1][2],
                        pr_t = oq[1][3], pr_xx = oq[1][4], pr_yy = oq[1][5];
            const float u = oq[2][0], u_x = oq[2][1], u_y = oq[2][2],
                        u_t = oq[2][3], u_xx = oq[2][4], u_yy = oq[2][5];
            const float v = oq[3][0], v_x = oq[3][1], v_y = oq[3][2],
                        v_t = oq[3][3], v_xx = oq[3][4], v_yy = oq[3][5];

            const float ig1 = 2.5f;
            const float ke = 0.5f * (u * u + v * v);
            const float E = pr * ig1 + rho * ke;
            const float d_x = u * u_x + v * v_x;
            const float d_y = u * u_y + v * v_y;
            const float d_t = u * u_t + v * v_t;
            const float E_x = pr_x * ig1 + rho_x * ke + rho * d_x;
            const float E_y = pr_y * ig1 + rho_y * ke + rho * d_y;
            const float E_t = pr_t * ig1 + rho_t * ke + rho * d_t;
            const float E_xx = pr_xx * ig1 + rho_xx * ke + 2.f * rho_x * d_x +
                               rho * (u_x * u_x + u * u_xx + v_x * v_x + v * v_xx);
            const float E_yy = pr_yy * ig1 + rho_yy * ke + 2.f * rho_y * d_y +
                               rho * (u_y * u_y + u * u_yy + v_y * v_y + v * v_yy);

            const float r1 = rho_t + (rho_x * u + rho * u_x) + (rho_y * v + rho * v_y)
                           - m * (rho_xx + rho_yy);
            const float r2 = (rho_t * u + rho * u_t)
                           + (rho_x * u * u + 2.f * rho * u * u_x + pr_x)
                           + (rho_y * u * v + rho * u_y * v + rho * u * v_y)
                           - m * ((rho_xx * u + 2.f * rho_x * u_x + rho * u_xx)
                                + (rho_yy * u + 2.f * rho_y * u_y + rho * u_yy));
            const float r3 = (rho_t * v + rho * v_t)
                           + (rho_x * u * v + rho * u_x * v + rho * u * v_x)
                           + (rho_y * v * v + 2.f * rho * v * v_y + pr_y)
                           - m * ((rho_xx * v + 2.f * rho_x * v_x + rho * v_xx)
                                + (rho_yy * v + 2.f * rho_y * v_y + rho * v_yy));
            const float r4 = E_t
                           + (u_x * (E + pr) + u * (E_x + pr_x))
                           + (v_y * (E + pr) + v * (E_y + pr_y))
                           - m * (E_xx + E_yy);
            if (tid < 32) {
                racc0 += r1 * r1; racc1 += r2 * r2;
                racc2 += r3 * r3; racc3 += r4 * r4;
            }
        }
        __syncthreads();
    }

    if (wv == 0) {  // lanes 32-63 hold zeros
        racc0 = wave_allsum(racc0);
        racc1 = wave_allsum(racc1);
        racc2 = wave_allsum(racc2);
        racc3 = wave_allsum(racc3);
        if (lane == 0) {
            resPart[blockIdx.x * 4 + 0] = racc0;
            resPart[blockIdx.x * 4 + 1] = racc1;
            resPart[blockIdx.x * 4 + 2] = racc2;
            resPart[blockIdx.x * 4 + 3] = racc3;
        }
    }
}

// ---------------- finalize: deterministic fixed-order combine ----------------
__global__ void k_fin(const float* __restrict__ resPart, const float* __restrict__ muPart,
                      const float* __restrict__ icPart, float* __restrict__ out) {
    const int lane = threadIdx.x;
    float r[4] = {0, 0, 0, 0};
    float m2 = 0.f;
    float qs[4] = {0, 0, 0, 0}, qc[4] = {0, 0, 0, 0};
    for (int b = lane; b < GRID; b += 64) {
#pragma unroll
        for (int i = 0; i < 4; i++) r[i] += resPart[b * 4 + i];
        m2 += muPart[b];
#pragma unroll
        for (int q = 0; q < 4; q++) {
            qs[q] += icPart[b * 8 + q];
            qc[q] += icPart[b * 8 + 4 + q];
        }
    }
#pragma unroll
    for (int i = 0; i < 4; i++) r[i] = wave_allsum(r[i]);
    m2 = wave_allsum(m2);
#pragma unroll
    for (int q = 0; q < 4; q++) { qs[q] = wave_allsum(qs[q]); qc[q] = wave_allsum(qc[q]); }
    if (lane == 0) {
        const float sumr = (r[0] + r[1] + r[2] + r[3]) / (float)NPTS;
        float init_loss = 0.f;
#pragma unroll
        for (int q = 0; q < 4; q++) init_loss += qs[q] / fmaxf(qc[q], 1.f);
        out[0] = sumr + 10.f * init_loss + 0.1f * (m2 / (float)NPTS);
    }
}

extern "C" void kernel_launch(void* const* d_in, const int* in_sizes, int n_in,
                              void* d_out, int out_size, void* d_ws, size_t ws_size,
                              hipStream_t stream) {
    const float* xtr = (const float*)d_in[0];
    const float* xin = (const float*)d_in[1];
    const float* icg = (const float*)d_in[2];
    const float* mw0 = (const float*)d_in[3];
    const float* mb0 = (const float*)d_in[4];
    const float* mw1 = (const float*)d_in[5];
    const float* mb1 = (const float*)d_in[6];
    const float* mw2 = (const float*)d_in[7];
    const float* mb2 = (const float*)d_in[8];
    const float* mw3 = (const float*)d_in[9];
    const float* mb3 = (const float*)d_in[10];
    const float* nw0 = (const float*)d_in[11];
    const float* nb0 = (const float*)d_in[12];
    const float* nw1 = (const float*)d_in[13];
    const float* nb1 = (const float*)d_in[14];
    const float* nw2 = (const float*)d_in[15];
    const float* nb2 = (const float*)d_in[16];
    const float* nw3 = (const float*)d_in[17];
    const float* nb3 = (const float*)d_in[18];

    float* wsf = (float*)d_ws;
    float* resPart = wsf;                                // 1024 f
    float* muPart = wsf + 1024;                          // 256 f
    float* icPart = wsf + 1280;                          // 2048 f
    unsigned short* wt1 = (unsigned short*)(wsf + 3328); // 16384 u16 each
    unsigned short* wt2 = wt1 + 16384;
    unsigned short* nt1 = wt2 + 16384;
    unsigned short* nt2 = nt1 + 16384;
    unsigned short* w3t = nt2 + 16384;                   // 2048 u16

    k_prep<<<5, BLK, 0, stream>>>(mw1, mw2, nw1, nw2, mw3, wt1, wt2, nt1, nt2, w3t);
    k_fused<<<GRID, BLK, 0, stream>>>(xtr, xin, icg,
                                      mw0, mb0, mb1, mb2, mw3, mb3,
                                      nw0, nb0, nb1, nb2, nw3, nb3,
                                      wt1, wt2, nt1, nt2, w3t,
                                      resPart, muPart, icPart);
    k_fin<<<1, 64, 0, stream>>>(resPart, muPart, icPart, (float*)d_out);
}